// Round 5
// baseline (454.050 us; speedup 1.0000x reference)
//
#include <hip/hip_runtime.h>
#include <hip/hip_bf16.h>
#include <math.h>

#define NN 10000      // nodes
#define EE 320000     // edges
#define BB 8          // batch
#define SS 12         // seq
#define PP 3          // pred
#define LL 3          // layers
#define BN (BB*NN)    // 80000 rows
#define CSR_CAP (EE + 8*NN + 32)     // padded-to-8 lists + prefetch slack
#define QSCL (0.25f * 1.44269504f)   // 1/sqrt(16) * log2(e)  -> exp2 domain

typedef __attribute__((ext_vector_type(8))) short bf8_t;   // 8 bf16 (4 VGPR)
typedef __attribute__((ext_vector_type(4))) float f4_t;

__device__ __forceinline__ float bf2f(unsigned short u) {
    unsigned int x = ((unsigned int)u) << 16;
    return __builtin_bit_cast(float, x);
}
__device__ __forceinline__ unsigned short f2bf(float f) {
    unsigned int u = __builtin_bit_cast(unsigned int, f);
    u += 0x7FFF + ((u >> 16) & 1);           // RNE
    return (unsigned short)(u >> 16);
}

// ---------------- input projection (+ bf16 shadow) ----------------
__global__ __launch_bounds__(256) void k_input_proj(const float* __restrict__ x,
                                                    const float* __restrict__ inW,
                                                    const float* __restrict__ inb,
                                                    float* __restrict__ h,
                                                    unsigned short* __restrict__ hb) {
    int idx = blockIdx.x * 256 + threadIdx.x;      // over BN*64
    if (idx >= BN * 64) return;
    int c  = idx & 63;
    int bn = idx >> 6;
    int n  = bn % NN;
    int b  = bn / NN;
    float s = inb[c];
#pragma unroll
    for (int t = 0; t < SS; ++t)
        s += x[(b * SS + t) * NN + n] * inW[t * 64 + c];
    h[idx]  = s;
    hb[idx] = f2bf(s);
}

// ---------------- CSR build ----------------
__global__ __launch_bounds__(256) void k_count(const int* __restrict__ ei, int* __restrict__ cnt) {
    int e = blockIdx.x * 256 + threadIdx.x;
    if (e >= EE) return;
    atomicAdd(&cnt[ei[EE + e]], 1);   // dst
}

// single block, 1024 threads, 10 nodes/thread serial + one block scan.
// outputs: rp[n] = padded start, degv[n] = real degree, cursor[n] = rp[n]
__global__ __launch_bounds__(1024) void k_scan(int* __restrict__ cnt,      // in: counts (== cursor buf)
                                               int* __restrict__ rp,
                                               int* __restrict__ degv) {
    __shared__ int ssum[1024];
    int t = threadIdx.x;
    int base = t * 10;
    int loc[10];
    int s = 0;
#pragma unroll
    for (int j = 0; j < 10; ++j) {
        int i = base + j;
        int d = (i < NN) ? cnt[i] : 0;
        loc[j] = d;
        s += (d + 7) & ~7;
    }
    ssum[t] = s;
    __syncthreads();
    for (int off = 1; off < 1024; off <<= 1) {
        int v = (t >= off) ? ssum[t - off] : 0;
        __syncthreads();
        ssum[t] += v;
        __syncthreads();
    }
    int run = ssum[t] - s;   // exclusive prefix of padded sizes
#pragma unroll
    for (int j = 0; j < 10; ++j) {
        int i = base + j;
        if (i < NN) {
            rp[i]   = run;
            degv[i] = loc[j];
            cnt[i]  = run;           // cursor for fill
            run += (loc[j] + 7) & ~7;
        }
    }
}

__global__ __launch_bounds__(256) void k_fill(const int* __restrict__ ei, int* __restrict__ cursor,
                                              int* __restrict__ csr) {
    int e = blockIdx.x * 256 + threadIdx.x;
    if (e >= EE) return;
    int dst = ei[EE + e];
    int pos = atomicAdd(&cursor[dst], 1);
    csr[pos] = ei[e] << 8;            // byte offset of 256B f32 row
}

// ---------------- weight prep: bf16, transposed [col][k]; q pre-scaled ----------------
__global__ __launch_bounds__(256) void k_wprep(const float* __restrict__ Wq, const float* __restrict__ Wk,
                                               const float* __restrict__ Wv, const float* __restrict__ Ws,
                                               const float* __restrict__ bq, const float* __restrict__ bk,
                                               const float* __restrict__ bv, const float* __restrict__ bs,
                                               unsigned short* __restrict__ wtb, float* __restrict__ bprep) {
    int idx = blockIdx.x * 256 + threadIdx.x;
    if (idx < LL * 4 * 64 * 64) {
        int l = idx >> 14; int j = (idx >> 12) & 3; int col = (idx >> 6) & 63; int k = idx & 63;
        const float* W = (j == 0 ? Wq : j == 1 ? Wk : j == 2 ? Wv : Ws) + l * 4096;
        float v = W[k * 64 + col];
        if (j == 0) v *= QSCL;
        wtb[idx] = f2bf(v);
    }
    if (idx < LL * 4 * 64) {
        int l = idx >> 8; int j = (idx >> 6) & 3; int c = idx & 63;
        const float* bsrc = (j == 0 ? bq : j == 1 ? bk : j == 2 ? bv : bs) + l * 64;
        bprep[idx] = bsrc[c] * (j == 0 ? QSCL : 1.0f);
    }
}

// ---------------- MFMA GEMM: one block per 64-row tile; wave w = matrix w ----------------
// w=0: qb (bf16, pre-scaled), w=1: kbuf, w=2: vbuf, w=3: h += skip
__global__ __launch_bounds__(256) void k_gemm(const unsigned short* __restrict__ hb,
                                              float* __restrict__ h,
                                              const unsigned short* __restrict__ wtb,   // + layer off
                                              const float* __restrict__ bprep,          // + layer off
                                              unsigned short* __restrict__ qb,
                                              float* __restrict__ kbuf, float* __restrict__ vbuf) {
    int tid = threadIdx.x;
    int l = tid & 63, w = tid >> 6;
    int row0 = blockIdx.x * 64;
    int colb = l & 15, kg = l >> 4;

    const unsigned short* wb = wtb + (size_t)w * 4096;   // [col][k]
    bf8_t bfr[2][4];
#pragma unroll
    for (int ks = 0; ks < 2; ++ks)
#pragma unroll
        for (int ct = 0; ct < 4; ++ct)
            bfr[ks][ct] = *(const bf8_t*)(wb + (ct * 16 + colb) * 64 + ks * 32 + kg * 8);

    bf8_t afr[2][4];
#pragma unroll
    for (int ks = 0; ks < 2; ++ks)
#pragma unroll
        for (int rt = 0; rt < 4; ++rt)
            afr[ks][rt] = *(const bf8_t*)(hb + (size_t)(row0 + rt * 16 + colb) * 64 + ks * 32 + kg * 8);

    f4_t acc[4][4];
#pragma unroll
    for (int rt = 0; rt < 4; ++rt)
#pragma unroll
        for (int ct = 0; ct < 4; ++ct)
            acc[rt][ct] = (f4_t){0.f, 0.f, 0.f, 0.f};
#pragma unroll
    for (int ks = 0; ks < 2; ++ks)
#pragma unroll
        for (int rt = 0; rt < 4; ++rt)
#pragma unroll
            for (int ct = 0; ct < 4; ++ct)
                acc[rt][ct] = __builtin_amdgcn_mfma_f32_16x16x32_bf16(afr[ks][rt], bfr[ks][ct],
                                                                      acc[rt][ct], 0, 0, 0);
    int rquad = l >> 4;     // D: col = l&15, row = rquad*4 + reg
#pragma unroll
    for (int ct = 0; ct < 4; ++ct) {
        int col = ct * 16 + colb;
        float bias = bprep[w * 64 + col];
#pragma unroll
        for (int rt = 0; rt < 4; ++rt)
#pragma unroll
            for (int r = 0; r < 4; ++r) {
                int row = row0 + rt * 16 + rquad * 4 + r;
                float val = acc[rt][ct][r] + bias;
                size_t off = (size_t)row * 64 + col;
                if      (w == 0) qb[off] = f2bf(val);
                else if (w == 1) kbuf[off] = val;
                else if (w == 2) vbuf[off] = val;
                else             h[off] += val;     // residual base = h + skip
            }
    }
}

// ---------------- fused attention gather + residual + layernorm (+ out proj on last) ----
// grid = 20000: b = bid&7 (XCD affinity), 4 nodes per block (one per wave)
// fixed softmax reference (m=0): logits are structurally bounded far below exp2 overflow
__global__ __launch_bounds__(256, 4) void k_attn_ln(const unsigned short* __restrict__ qb,
                                                    const float* __restrict__ kbuf,
                                                    const float* __restrict__ vbuf,
                                                    const int* __restrict__ rp,
                                                    const int* __restrict__ degv,
                                                    const int* __restrict__ csr,
                                                    const float* __restrict__ lng,
                                                    const float* __restrict__ lnb,
                                                    float* __restrict__ h,
                                                    unsigned short* __restrict__ hb,
                                                    const float* __restrict__ oW,   // null except last layer
                                                    const float* __restrict__ ob,
                                                    float* __restrict__ out) {
    int b    = blockIdx.x & 7;
    int n    = ((blockIdx.x >> 3) << 2) | __builtin_amdgcn_readfirstlane(threadIdx.x >> 6);
    int lane = threadIdx.x & 63;
    int lg   = lane & 15;       // channel block: channels 4*lg..4*lg+3, head = lg>>2
    int grp  = lane >> 4;       // edge group 0..3
    size_t wid = (size_t)b * NN + n;

    const char* kbase = (const char*)kbuf + (size_t)b * NN * 256;   // wave-uniform
    const char* vbase = (const char*)vbuf + (size_t)b * NN * 256;
    int lgoff = lg * 16;

    ushort4 qu = ((const ushort4*)qb)[wid * 16 + lg];
    float4 q4 = {bf2f(qu.x), bf2f(qu.y), bf2f(qu.z), bf2f(qu.w)};   // already *0.25*log2e

    int e0 = rp[n], deg = degv[n];
    int e1 = e0 + deg;
    float den = 0.f;
    float4 av = {0.f, 0.f, 0.f, 0.f};

    // prologue loads for iteration 0 (slack-padded csr: always safe)
    {
        int c0 = csr[e0 + grp], c1 = csr[e0 + grp + 4];
        unsigned o0 = (unsigned)(c0 + lgoff), o1 = (unsigned)(c1 + lgoff);
        float4 ka = *(const float4*)(kbase + o0);
        float4 va = *(const float4*)(vbase + o0);
        float4 kc = *(const float4*)(kbase + o1);
        float4 vc = *(const float4*)(vbase + o1);

        for (int e = e0; e < e1; e += 8) {
            // software prefetch of next iteration (regs; slack keeps it in-bounds)
            int c0n = csr[e + 8 + grp], c1n = csr[e + 12 + grp];
            unsigned p0 = (unsigned)(c0n + lgoff), p1 = (unsigned)(c1n + lgoff);
            float4 kan = *(const float4*)(kbase + p0);
            float4 van = *(const float4*)(vbase + p0);
            float4 kcn = *(const float4*)(kbase + p1);
            float4 vcn = *(const float4*)(vbase + p1);

            float val0 = (e + grp     < e1) ? 1.f : 0.f;
            float val1 = (e + grp + 4 < e1) ? 1.f : 0.f;
            float d0 = ka.x * q4.x + ka.y * q4.y + ka.z * q4.z + ka.w * q4.w;
            float d1 = kc.x * q4.x + kc.y * q4.y + kc.z * q4.z + kc.w * q4.w;
            d0 += __shfl_xor(d0, 1); d0 += __shfl_xor(d0, 2);   // per-head dot (log2 domain)
            d1 += __shfl_xor(d1, 1); d1 += __shfl_xor(d1, 2);

            float w0 = val0 * __builtin_amdgcn_exp2f(d0);
            float w1 = val1 * __builtin_amdgcn_exp2f(d1);
            den += w0 + w1;
            av.x += w0 * va.x + w1 * vc.x; av.y += w0 * va.y + w1 * vc.y;
            av.z += w0 * va.z + w1 * vc.z; av.w += w0 * va.w + w1 * vc.w;

            ka = kan; va = van; kc = kcn; vc = vcn;
        }
    }

    // merge the 4 edge-groups: pure sums (shared softmax reference)
#pragma unroll
    for (int off = 16; off <= 32; off <<= 1) {
        den  += __shfl_xor(den, off);
        av.x += __shfl_xor(av.x, off); av.y += __shfl_xor(av.y, off);
        av.z += __shfl_xor(av.z, off); av.w += __shfl_xor(av.w, off);
    }
    float inv = (den > 0.f) ? __builtin_amdgcn_rcpf(den) : 0.f;

    // residual (h already holds h + skip) + layernorm
    float4 h4 = ((const float4*)h)[wid * 16 + lg];
    float4 x4;
    x4.x = h4.x + av.x * inv; x4.y = h4.y + av.y * inv;
    x4.z = h4.z + av.z * inv; x4.w = h4.w + av.w * inv;

    float s = x4.x + x4.y + x4.z + x4.w;
#pragma unroll
    for (int off = 1; off < 16; off <<= 1) s += __shfl_xor(s, off);
    float mu = s * (1.f / 64.f);
    float4 dx;
    dx.x = x4.x - mu; dx.y = x4.y - mu; dx.z = x4.z - mu; dx.w = x4.w - mu;
    float vs = dx.x * dx.x + dx.y * dx.y + dx.z * dx.z + dx.w * dx.w;
#pragma unroll
    for (int off = 1; off < 16; off <<= 1) vs += __shfl_xor(vs, off);
    float r = __builtin_amdgcn_rsqf(vs * (1.f / 64.f) + 1e-5f);

    float4 g4 = ((const float4*)lng)[lg];
    float4 b4 = ((const float4*)lnb)[lg];
    float4 o4;
    o4.x = dx.x * r * g4.x + b4.x; o4.y = dx.y * r * g4.y + b4.y;
    o4.z = dx.z * r * g4.z + b4.z; o4.w = dx.w * r * g4.w + b4.w;

    if (oW) {
        // fused output projection: t_p = sum_c o4[c] * oW[c][p]; reduce over 16 lanes
        int c0 = lg * 4;
        float t0 = o4.x * oW[(c0+0)*3+0] + o4.y * oW[(c0+1)*3+0] + o4.z * oW[(c0+2)*3+0] + o4.w * oW[(c0+3)*3+0];
        float t1 = o4.x * oW[(c0+0)*3+1] + o4.y * oW[(c0+1)*3+1] + o4.z * oW[(c0+2)*3+1] + o4.w * oW[(c0+3)*3+1];
        float t2 = o4.x * oW[(c0+0)*3+2] + o4.y * oW[(c0+1)*3+2] + o4.z * oW[(c0+2)*3+2] + o4.w * oW[(c0+3)*3+2];
#pragma unroll
        for (int off = 1; off < 16; off <<= 1) {
            t0 += __shfl_xor(t0, off); t1 += __shfl_xor(t1, off); t2 += __shfl_xor(t2, off);
        }
        if (lane == 0) {
            out[((size_t)b * PP + 0) * NN + n] = t0 + ob[0];
            out[((size_t)b * PP + 1) * NN + n] = t1 + ob[1];
            out[((size_t)b * PP + 2) * NN + n] = t2 + ob[2];
        }
    } else if (lane < 16) {
        ((float4*)h)[wid * 16 + lg] = o4;
        ushort4 hu = {f2bf(o4.x), f2bf(o4.y), f2bf(o4.z), f2bf(o4.w)};
        ((ushort4*)hb)[wid * 16 + lg] = hu;
    }
}

extern "C" void kernel_launch(void* const* d_in, const int* in_sizes, int n_in,
                              void* d_out, int out_size, void* d_ws, size_t ws_size,
                              hipStream_t stream) {
    const float* x    = (const float*)d_in[0];
    const int*   ei   = (const int*)  d_in[1];
    const float* inW  = (const float*)d_in[2];
    const float* inb  = (const float*)d_in[3];
    const float* Wq   = (const float*)d_in[4];
    const float* bq   = (const float*)d_in[5];
    const float* Wk   = (const float*)d_in[6];
    const float* bk   = (const float*)d_in[7];
    const float* Wv   = (const float*)d_in[8];
    const float* bv   = (const float*)d_in[9];
    const float* Wsk  = (const float*)d_in[10];
    const float* bsk  = (const float*)d_in[11];
    const float* lng  = (const float*)d_in[12];
    const float* lnb  = (const float*)d_in[13];
    const float* outW = (const float*)d_in[14];
    const float* outb = (const float*)d_in[15];
    float* out = (float*)d_out;

    float* h    = (float*)d_ws;                         // BN*64 f32
    float* kbuf = h    + (size_t)BN * 64;
    float* vbuf = kbuf + (size_t)BN * 64;
    unsigned short* hb = (unsigned short*)(vbuf + (size_t)BN * 64);   // BN*64 bf16
    unsigned short* qb = hb + (size_t)BN * 64;                        // BN*64 bf16
    int* rp      = (int*)(qb + (size_t)BN * 64);
    int* degv    = rp + NN;
    int* cursor  = degv + NN;
    int* csr     = cursor + NN;                          // CSR_CAP entries
    unsigned short* wtb = (unsigned short*)(csr + CSR_CAP);  // LL*4*64*64 bf16
    float* bprep = (float*)(wtb + LL * 4 * 64 * 64);         // LL*4*64 f32

    // CSR build + weight prep (edge list/weights constant across layers/batches)
    hipMemsetAsync(cursor, 0, (NN + CSR_CAP) * sizeof(int), stream);   // cursor + csr
    k_count<<<(EE + 255) / 256, 256, 0, stream>>>(ei, cursor);
    k_scan <<<1, 1024, 0, stream>>>(cursor, rp, degv);
    k_fill <<<(EE + 255) / 256, 256, 0, stream>>>(ei, cursor, csr);
    k_wprep<<<(LL * 4 * 64 * 64 + 255) / 256, 256, 0, stream>>>(Wq, Wk, Wv, Wsk, bq, bk, bv, bsk,
                                                                wtb, bprep);

    k_input_proj<<<(BN * 64 + 255) / 256, 256, 0, stream>>>(x, inW, inb, h, hb);

    for (int l = 0; l < LL; ++l) {
        k_gemm<<<BN / 64, 256, 0, stream>>>(hb, h, wtb + (size_t)l * 4 * 4096,
                                            bprep + (size_t)l * 4 * 64, qb, kbuf, vbuf);
        k_attn_ln<<<BN / 4, 256, 0, stream>>>(qb, kbuf, vbuf, rp, degv, csr,
                                              lng, lnb, h, hb,
                                              (l == LL - 1) ? outW : nullptr, outb, out);
    }
}

// Round 6
// 443.780 us; speedup vs baseline: 1.0231x; 1.0231x over previous
//
#include <hip/hip_runtime.h>
#include <hip/hip_bf16.h>
#include <math.h>

#define NN 10000      // nodes
#define EE 320000     // edges
#define BB 8          // batch
#define SS 12         // seq
#define PP 3          // pred
#define LL 3          // layers
#define BN (BB*NN)    // 80000 rows
#define CSR_CAP (EE + 16*NN + 64)    // padded-to-16 lists + slack
#define QSCL (0.25f * 1.44269504f)   // 1/sqrt(16) * log2(e)  -> exp2 domain

typedef __attribute__((ext_vector_type(8))) short bf8_t;   // 8 bf16 (4 VGPR)
typedef __attribute__((ext_vector_type(4))) float f4_t;

__device__ __forceinline__ float bf2f(unsigned short u) {
    unsigned int x = ((unsigned int)u) << 16;
    return __builtin_bit_cast(float, x);
}
__device__ __forceinline__ unsigned short f2bf(float f) {
    unsigned int u = __builtin_bit_cast(unsigned int, f);
    u += 0x7FFF + ((u >> 16) & 1);           // RNE
    return (unsigned short)(u >> 16);
}

// ---------------- input projection (+ bf16 shadow) ----------------
__global__ __launch_bounds__(256) void k_input_proj(const float* __restrict__ x,
                                                    const float* __restrict__ inW,
                                                    const float* __restrict__ inb,
                                                    float* __restrict__ h,
                                                    unsigned short* __restrict__ hb) {
    int idx = blockIdx.x * 256 + threadIdx.x;      // over BN*64
    if (idx >= BN * 64) return;
    int c  = idx & 63;
    int bn = idx >> 6;
    int n  = bn % NN;
    int b  = bn / NN;
    float s = inb[c];
#pragma unroll
    for (int t = 0; t < SS; ++t)
        s += x[(b * SS + t) * NN + n] * inW[t * 64 + c];
    h[idx]  = s;
    hb[idx] = f2bf(s);
}

// ---------------- CSR build ----------------
__global__ __launch_bounds__(256) void k_count(const int* __restrict__ ei, int* __restrict__ cnt) {
    int e = blockIdx.x * 256 + threadIdx.x;
    if (e >= EE) return;
    atomicAdd(&cnt[ei[EE + e]], 1);   // dst
}

// single block, 1024 threads, 10 nodes/thread serial + one block scan.
// outputs: rp[n] = padded start (pad-16), degv[n] = real degree, cursor[n] = rp[n]
__global__ __launch_bounds__(1024) void k_scan(int* __restrict__ cnt,      // in: counts (== cursor buf)
                                               int* __restrict__ rp,
                                               int* __restrict__ degv) {
    __shared__ int ssum[1024];
    int t = threadIdx.x;
    int base = t * 10;
    int loc[10];
    int s = 0;
#pragma unroll
    for (int j = 0; j < 10; ++j) {
        int i = base + j;
        int d = (i < NN) ? cnt[i] : 0;
        loc[j] = d;
        s += (d + 15) & ~15;
    }
    ssum[t] = s;
    __syncthreads();
    for (int off = 1; off < 1024; off <<= 1) {
        int v = (t >= off) ? ssum[t - off] : 0;
        __syncthreads();
        ssum[t] += v;
        __syncthreads();
    }
    int run = ssum[t] - s;   // exclusive prefix of padded sizes
#pragma unroll
    for (int j = 0; j < 10; ++j) {
        int i = base + j;
        if (i < NN) {
            rp[i]   = run;
            degv[i] = loc[j];
            cnt[i]  = run;           // cursor for fill
            run += (loc[j] + 15) & ~15;
        }
    }
}

__global__ __launch_bounds__(256) void k_fill(const int* __restrict__ ei, int* __restrict__ cursor,
                                              int* __restrict__ csr) {
    int e = blockIdx.x * 256 + threadIdx.x;
    if (e >= EE) return;
    int dst = ei[EE + e];
    int pos = atomicAdd(&cursor[dst], 1);
    csr[pos] = ei[e] << 7;            // byte offset of 128B bf16 row
}

// ---------------- weight prep: bf16, transposed [col][k]; q pre-scaled ----------------
__global__ __launch_bounds__(256) void k_wprep(const float* __restrict__ Wq, const float* __restrict__ Wk,
                                               const float* __restrict__ Wv, const float* __restrict__ Ws,
                                               const float* __restrict__ bq, const float* __restrict__ bk,
                                               const float* __restrict__ bv, const float* __restrict__ bs,
                                               unsigned short* __restrict__ wtb, float* __restrict__ bprep) {
    int idx = blockIdx.x * 256 + threadIdx.x;
    if (idx < LL * 4 * 64 * 64) {
        int l = idx >> 14; int j = (idx >> 12) & 3; int col = (idx >> 6) & 63; int k = idx & 63;
        const float* W = (j == 0 ? Wq : j == 1 ? Wk : j == 2 ? Wv : Ws) + l * 4096;
        float v = W[k * 64 + col];
        if (j == 0) v *= QSCL;
        wtb[idx] = f2bf(v);
    }
    if (idx < LL * 4 * 64) {
        int l = idx >> 8; int j = (idx >> 6) & 3; int c = idx & 63;
        const float* bsrc = (j == 0 ? bq : j == 1 ? bk : j == 2 ? bv : bs) + l * 64;
        bprep[idx] = bsrc[c] * (j == 0 ? QSCL : 1.0f);
    }
}

// ---------------- MFMA GEMM: one block per 64-row tile; wave w = matrix w ----------------
// w=0: qb (bf16, pre-scaled), w=1: kb (bf16), w=2: vb (bf16), w=3: h += skip
__global__ __launch_bounds__(256) void k_gemm(const unsigned short* __restrict__ hb,
                                              float* __restrict__ h,
                                              const unsigned short* __restrict__ wtb,   // + layer off
                                              const float* __restrict__ bprep,          // + layer off
                                              unsigned short* __restrict__ qb,
                                              unsigned short* __restrict__ kb,
                                              unsigned short* __restrict__ vb) {
    int tid = threadIdx.x;
    int l = tid & 63, w = tid >> 6;
    int row0 = blockIdx.x * 64;
    int colb = l & 15, kg = l >> 4;

    const unsigned short* wb = wtb + (size_t)w * 4096;   // [col][k]
    bf8_t bfr[2][4];
#pragma unroll
    for (int ks = 0; ks < 2; ++ks)
#pragma unroll
        for (int ct = 0; ct < 4; ++ct)
            bfr[ks][ct] = *(const bf8_t*)(wb + (ct * 16 + colb) * 64 + ks * 32 + kg * 8);

    bf8_t afr[2][4];
#pragma unroll
    for (int ks = 0; ks < 2; ++ks)
#pragma unroll
        for (int rt = 0; rt < 4; ++rt)
            afr[ks][rt] = *(const bf8_t*)(hb + (size_t)(row0 + rt * 16 + colb) * 64 + ks * 32 + kg * 8);

    f4_t acc[4][4];
#pragma unroll
    for (int rt = 0; rt < 4; ++rt)
#pragma unroll
        for (int ct = 0; ct < 4; ++ct)
            acc[rt][ct] = (f4_t){0.f, 0.f, 0.f, 0.f};
#pragma unroll
    for (int ks = 0; ks < 2; ++ks)
#pragma unroll
        for (int rt = 0; rt < 4; ++rt)
#pragma unroll
            for (int ct = 0; ct < 4; ++ct)
                acc[rt][ct] = __builtin_amdgcn_mfma_f32_16x16x32_bf16(afr[ks][rt], bfr[ks][ct],
                                                                      acc[rt][ct], 0, 0, 0);
    int rquad = l >> 4;     // D: col = l&15, row = rquad*4 + reg
#pragma unroll
    for (int ct = 0; ct < 4; ++ct) {
        int col = ct * 16 + colb;
        float bias = bprep[w * 64 + col];
#pragma unroll
        for (int rt = 0; rt < 4; ++rt)
#pragma unroll
            for (int r = 0; r < 4; ++r) {
                int row = row0 + rt * 16 + rquad * 4 + r;
                float val = acc[rt][ct][r] + bias;
                size_t off = (size_t)row * 64 + col;
                if      (w == 0) qb[off] = f2bf(val);
                else if (w == 1) kb[off] = f2bf(val);
                else if (w == 2) vb[off] = f2bf(val);
                else             h[off] += val;     // residual base = h + skip
            }
    }
}

// ---------------- fused attention gather + residual + layernorm (+ out proj on last) ----
// grid = 20000: b = bid&7 (XCD affinity; bf16 k+v per batch = 2.5MB fits 4MB L2)
// 16 edges/wave/iter: 4 per 16-lane group, 8 independent 8B loads in flight per lane
__global__ __launch_bounds__(256, 4) void k_attn_ln(const unsigned short* __restrict__ qb,
                                                    const unsigned short* __restrict__ kb,
                                                    const unsigned short* __restrict__ vb,
                                                    const int* __restrict__ rp,
                                                    const int* __restrict__ degv,
                                                    const int* __restrict__ csr,
                                                    const float* __restrict__ lng,
                                                    const float* __restrict__ lnb,
                                                    float* __restrict__ h,
                                                    unsigned short* __restrict__ hb,
                                                    const float* __restrict__ oW,   // null except last layer
                                                    const float* __restrict__ ob,
                                                    float* __restrict__ out) {
    int b    = blockIdx.x & 7;
    int n    = ((blockIdx.x >> 3) << 2) | __builtin_amdgcn_readfirstlane(threadIdx.x >> 6);
    int lane = threadIdx.x & 63;
    int lg   = lane & 15;       // channel block: channels 4*lg..4*lg+3, head = lg>>2
    int grp  = lane >> 4;       // edge sub-slot 0..3
    size_t wid = (size_t)b * NN + n;

    const char* kbase = (const char*)kb + (size_t)b * NN * 128;   // wave-uniform
    const char* vbase = (const char*)vb + (size_t)b * NN * 128;
    int lgoff = lg * 8;

    ushort4 qu = ((const ushort4*)qb)[wid * 16 + lg];
    float4 q4 = {bf2f(qu.x), bf2f(qu.y), bf2f(qu.z), bf2f(qu.w)};   // already *0.25*log2e

    int e0 = rp[n], deg = degv[n];
    int e1 = e0 + deg;
    float den0 = 0.f, den1 = 0.f;
    float4 av0 = {0.f, 0.f, 0.f, 0.f}, av1 = {0.f, 0.f, 0.f, 0.f};

    for (int e = e0; e < e1; e += 16) {
        // 4 edges per 16-lane group; padded-to-16 lists keep all csr reads in-bounds
        int c0 = csr[e + grp];
        int c1 = csr[e + 4 + grp];
        int c2 = csr[e + 8 + grp];
        int c3 = csr[e + 12 + grp];
        unsigned o0 = (unsigned)(c0 + lgoff), o1 = (unsigned)(c1 + lgoff);
        unsigned o2 = (unsigned)(c2 + lgoff), o3 = (unsigned)(c3 + lgoff);
        ushort4 k0 = *(const ushort4*)(kbase + o0);
        ushort4 k1 = *(const ushort4*)(kbase + o1);
        ushort4 k2 = *(const ushort4*)(kbase + o2);
        ushort4 k3 = *(const ushort4*)(kbase + o3);
        ushort4 v0 = *(const ushort4*)(vbase + o0);
        ushort4 v1 = *(const ushort4*)(vbase + o1);
        ushort4 v2 = *(const ushort4*)(vbase + o2);
        ushort4 v3 = *(const ushort4*)(vbase + o3);

        float m0 = (e + grp      < e1) ? 1.f : 0.f;
        float m1 = (e + 4 + grp  < e1) ? 1.f : 0.f;
        float m2 = (e + 8 + grp  < e1) ? 1.f : 0.f;
        float m3 = (e + 12 + grp < e1) ? 1.f : 0.f;

        float d0 = bf2f(k0.x)*q4.x + bf2f(k0.y)*q4.y + bf2f(k0.z)*q4.z + bf2f(k0.w)*q4.w;
        float d1 = bf2f(k1.x)*q4.x + bf2f(k1.y)*q4.y + bf2f(k1.z)*q4.z + bf2f(k1.w)*q4.w;
        float d2 = bf2f(k2.x)*q4.x + bf2f(k2.y)*q4.y + bf2f(k2.z)*q4.z + bf2f(k2.w)*q4.w;
        float d3 = bf2f(k3.x)*q4.x + bf2f(k3.y)*q4.y + bf2f(k3.z)*q4.z + bf2f(k3.w)*q4.w;
        d0 += __shfl_xor(d0, 1); d0 += __shfl_xor(d0, 2);   // per-head dot (log2 domain)
        d1 += __shfl_xor(d1, 1); d1 += __shfl_xor(d1, 2);
        d2 += __shfl_xor(d2, 1); d2 += __shfl_xor(d2, 2);
        d3 += __shfl_xor(d3, 1); d3 += __shfl_xor(d3, 2);

        float w0 = m0 * __builtin_amdgcn_exp2f(d0);
        float w1 = m1 * __builtin_amdgcn_exp2f(d1);
        float w2 = m2 * __builtin_amdgcn_exp2f(d2);
        float w3 = m3 * __builtin_amdgcn_exp2f(d3);

        den0 += w0 + w1;
        den1 += w2 + w3;
        av0.x += w0 * bf2f(v0.x) + w1 * bf2f(v1.x);
        av0.y += w0 * bf2f(v0.y) + w1 * bf2f(v1.y);
        av0.z += w0 * bf2f(v0.z) + w1 * bf2f(v1.z);
        av0.w += w0 * bf2f(v0.w) + w1 * bf2f(v1.w);
        av1.x += w2 * bf2f(v2.x) + w3 * bf2f(v3.x);
        av1.y += w2 * bf2f(v2.y) + w3 * bf2f(v3.y);
        av1.z += w2 * bf2f(v2.z) + w3 * bf2f(v3.z);
        av1.w += w2 * bf2f(v2.w) + w3 * bf2f(v3.w);
    }

    float den = den0 + den1;
    float4 av = {av0.x + av1.x, av0.y + av1.y, av0.z + av1.z, av0.w + av1.w};

    // merge the 4 edge-groups: pure sums (shared softmax reference m=0)
#pragma unroll
    for (int off = 16; off <= 32; off <<= 1) {
        den  += __shfl_xor(den, off);
        av.x += __shfl_xor(av.x, off); av.y += __shfl_xor(av.y, off);
        av.z += __shfl_xor(av.z, off); av.w += __shfl_xor(av.w, off);
    }
    float inv = (den > 0.f) ? __builtin_amdgcn_rcpf(den) : 0.f;

    // residual (h already holds h + skip) + layernorm
    float4 h4 = ((const float4*)h)[wid * 16 + lg];
    float4 x4;
    x4.x = h4.x + av.x * inv; x4.y = h4.y + av.y * inv;
    x4.z = h4.z + av.z * inv; x4.w = h4.w + av.w * inv;

    float s = x4.x + x4.y + x4.z + x4.w;
#pragma unroll
    for (int off = 1; off < 16; off <<= 1) s += __shfl_xor(s, off);
    float mu = s * (1.f / 64.f);
    float4 dx;
    dx.x = x4.x - mu; dx.y = x4.y - mu; dx.z = x4.z - mu; dx.w = x4.w - mu;
    float vs = dx.x * dx.x + dx.y * dx.y + dx.z * dx.z + dx.w * dx.w;
#pragma unroll
    for (int off = 1; off < 16; off <<= 1) vs += __shfl_xor(vs, off);
    float r = __builtin_amdgcn_rsqf(vs * (1.f / 64.f) + 1e-5f);

    float4 g4 = ((const float4*)lng)[lg];
    float4 b4 = ((const float4*)lnb)[lg];
    float4 o4;
    o4.x = dx.x * r * g4.x + b4.x; o4.y = dx.y * r * g4.y + b4.y;
    o4.z = dx.z * r * g4.z + b4.z; o4.w = dx.w * r * g4.w + b4.w;

    if (oW) {
        // fused output projection: t_p = sum_c o4[c] * oW[c][p]; reduce over 16 lanes
        int c0 = lg * 4;
        float t0 = o4.x * oW[(c0+0)*3+0] + o4.y * oW[(c0+1)*3+0] + o4.z * oW[(c0+2)*3+0] + o4.w * oW[(c0+3)*3+0];
        float t1 = o4.x * oW[(c0+0)*3+1] + o4.y * oW[(c0+1)*3+1] + o4.z * oW[(c0+2)*3+1] + o4.w * oW[(c0+3)*3+1];
        float t2 = o4.x * oW[(c0+0)*3+2] + o4.y * oW[(c0+1)*3+2] + o4.z * oW[(c0+2)*3+2] + o4.w * oW[(c0+3)*3+2];
#pragma unroll
        for (int off = 1; off < 16; off <<= 1) {
            t0 += __shfl_xor(t0, off); t1 += __shfl_xor(t1, off); t2 += __shfl_xor(t2, off);
        }
        if (lane == 0) {
            out[((size_t)b * PP + 0) * NN + n] = t0 + ob[0];
            out[((size_t)b * PP + 1) * NN + n] = t1 + ob[1];
            out[((size_t)b * PP + 2) * NN + n] = t2 + ob[2];
        }
    } else if (lane < 16) {
        ((float4*)h)[wid * 16 + lg] = o4;
        ushort4 hu = {f2bf(o4.x), f2bf(o4.y), f2bf(o4.z), f2bf(o4.w)};
        ((ushort4*)hb)[wid * 16 + lg] = hu;
    }
}

extern "C" void kernel_launch(void* const* d_in, const int* in_sizes, int n_in,
                              void* d_out, int out_size, void* d_ws, size_t ws_size,
                              hipStream_t stream) {
    const float* x    = (const float*)d_in[0];
    const int*   ei   = (const int*)  d_in[1];
    const float* inW  = (const float*)d_in[2];
    const float* inb  = (const float*)d_in[3];
    const float* Wq   = (const float*)d_in[4];
    const float* bq   = (const float*)d_in[5];
    const float* Wk   = (const float*)d_in[6];
    const float* bk   = (const float*)d_in[7];
    const float* Wv   = (const float*)d_in[8];
    const float* bv   = (const float*)d_in[9];
    const float* Wsk  = (const float*)d_in[10];
    const float* bsk  = (const float*)d_in[11];
    const float* lng  = (const float*)d_in[12];
    const float* lnb  = (const float*)d_in[13];
    const float* outW = (const float*)d_in[14];
    const float* outb = (const float*)d_in[15];
    float* out = (float*)d_out;

    float* h    = (float*)d_ws;                                       // BN*64 f32
    unsigned short* hb = (unsigned short*)(h + (size_t)BN * 64);      // BN*64 bf16
    unsigned short* qb = hb + (size_t)BN * 64;                        // BN*64 bf16
    unsigned short* kb = qb + (size_t)BN * 64;                        // BN*64 bf16
    unsigned short* vb = kb + (size_t)BN * 64;                        // BN*64 bf16
    int* rp      = (int*)(vb + (size_t)BN * 64);
    int* degv    = rp + NN;
    int* cursor  = degv + NN;
    int* csr     = cursor + NN;                          // CSR_CAP entries
    unsigned short* wtb = (unsigned short*)(csr + CSR_CAP);  // LL*4*64*64 bf16
    float* bprep = (float*)(wtb + LL * 4 * 64 * 64);         // LL*4*64 f32

    // CSR build + weight prep (edge list/weights constant across layers/batches)
    hipMemsetAsync(cursor, 0, (NN + CSR_CAP) * sizeof(int), stream);   // cursor + csr
    k_count<<<(EE + 255) / 256, 256, 0, stream>>>(ei, cursor);
    k_scan <<<1, 1024, 0, stream>>>(cursor, rp, degv);
    k_fill <<<(EE + 255) / 256, 256, 0, stream>>>(ei, cursor, csr);
    k_wprep<<<(LL * 4 * 64 * 64 + 255) / 256, 256, 0, stream>>>(Wq, Wk, Wv, Wsk, bq, bk, bv, bsk,
                                                                wtb, bprep);

    k_input_proj<<<(BN * 64 + 255) / 256, 256, 0, stream>>>(x, inW, inb, h, hb);

    for (int l = 0; l < LL; ++l) {
        k_gemm<<<BN / 64, 256, 0, stream>>>(hb, h, wtb + (size_t)l * 4 * 4096,
                                            bprep + (size_t)l * 4 * 64, qb, kb, vb);
        k_attn_ln<<<BN / 4, 256, 0, stream>>>(qb, kb, vb, rp, degv, csr,
                                              lng, lnb, h, hb,
                                              (l == LL - 1) ? outW : nullptr, outb, out);
    }
}

// Round 7
// 421.604 us; speedup vs baseline: 1.0770x; 1.0526x over previous
//
#include <hip/hip_runtime.h>
#include <hip/hip_bf16.h>
#include <math.h>

#define NN 10000      // nodes
#define EE 320000     // edges
#define BB 8          // batch
#define SS 12         // seq
#define PP 3          // pred
#define LL 3          // layers
#define BN (BB*NN)    // 80000 rows
#define CSR_CAP (EE + 16*NN + 64)    // padded-to-16 lists + slack
#define QSCL (0.25f * 1.44269504f)   // 1/sqrt(16) * log2(e)  -> exp2 domain

typedef __attribute__((ext_vector_type(8))) short bf8_t;   // 8 bf16 (4 VGPR)
typedef __attribute__((ext_vector_type(4))) float f4_t;

__device__ __forceinline__ float bf2f(unsigned short u) {
    unsigned int x = ((unsigned int)u) << 16;
    return __builtin_bit_cast(float, x);
}
__device__ __forceinline__ unsigned short f2bf(float f) {
    unsigned int u = __builtin_bit_cast(unsigned int, f);
    u += 0x7FFF + ((u >> 16) & 1);           // RNE
    return (unsigned short)(u >> 16);
}
__device__ __forceinline__ unsigned short f2h(float f) {
    _Float16 h = (_Float16)f;
    return __builtin_bit_cast(unsigned short, h);
}
// v_dot2_f32_f16: d = a.h0*b.h0 + a.h1*b.h1 + c   (packed half2 in 32-bit regs)
__device__ __forceinline__ float dot2(unsigned a, unsigned b, float c) {
    float d;
    asm("v_dot2_f32_f16 %0, %1, %2, %3" : "=v"(d) : "v"(a), "v"(b), "v"(c));
    return d;
}
// DPP add-reduce helpers (pure VALU; bound_ctrl=1)
template<int CTRL>
__device__ __forceinline__ float dppadd(float x) {
    int t = __builtin_amdgcn_update_dpp(0, __builtin_bit_cast(int, x), CTRL, 0xF, 0xF, true);
    return x + __builtin_bit_cast(float, t);
}
#define QX1 0xB1   // quad_perm [1,0,3,2]  == xor1
#define QX2 0x4E   // quad_perm [2,3,0,1]  == xor2
#define RR4 0x124  // row_ror:4
#define RR8 0x128  // row_ror:8
__device__ __forceinline__ float quad_sum(float x) {         // sum over 4 quad lanes
    x = dppadd<QX1>(x); x = dppadd<QX2>(x); return x;
}
__device__ __forceinline__ float row_sum(float x) {          // sum over 16-lane row
    x = dppadd<QX1>(x); x = dppadd<QX2>(x);
    x = dppadd<RR4>(x); x = dppadd<RR8>(x); return x;
}

// ---------------- input projection (+ bf16 shadow) ----------------
__global__ __launch_bounds__(256) void k_input_proj(const float* __restrict__ x,
                                                    const float* __restrict__ inW,
                                                    const float* __restrict__ inb,
                                                    float* __restrict__ h,
                                                    unsigned short* __restrict__ hb) {
    int idx = blockIdx.x * 256 + threadIdx.x;      // over BN*64
    if (idx >= BN * 64) return;
    int c  = idx & 63;
    int bn = idx >> 6;
    int n  = bn % NN;
    int b  = bn / NN;
    float s = inb[c];
#pragma unroll
    for (int t = 0; t < SS; ++t)
        s += x[(b * SS + t) * NN + n] * inW[t * 64 + c];
    h[idx]  = s;
    hb[idx] = f2bf(s);
}

// ---------------- CSR build ----------------
__global__ __launch_bounds__(256) void k_count(const int* __restrict__ ei, int* __restrict__ cnt) {
    int e = blockIdx.x * 256 + threadIdx.x;
    if (e >= EE) return;
    atomicAdd(&cnt[ei[EE + e]], 1);   // dst
}

// single block, 1024 threads, 10 nodes/thread serial + one block scan.
// outputs: rp[n] = padded start (pad-16), degv[n] = real degree, cursor[n] = rp[n]
__global__ __launch_bounds__(1024) void k_scan(int* __restrict__ cnt,      // in: counts (== cursor buf)
                                               int* __restrict__ rp,
                                               int* __restrict__ degv) {
    __shared__ int ssum[1024];
    int t = threadIdx.x;
    int base = t * 10;
    int loc[10];
    int s = 0;
#pragma unroll
    for (int j = 0; j < 10; ++j) {
        int i = base + j;
        int d = (i < NN) ? cnt[i] : 0;
        loc[j] = d;
        s += (d + 15) & ~15;
    }
    ssum[t] = s;
    __syncthreads();
    for (int off = 1; off < 1024; off <<= 1) {
        int v = (t >= off) ? ssum[t - off] : 0;
        __syncthreads();
        ssum[t] += v;
        __syncthreads();
    }
    int run = ssum[t] - s;   // exclusive prefix of padded sizes
#pragma unroll
    for (int j = 0; j < 10; ++j) {
        int i = base + j;
        if (i < NN) {
            rp[i]   = run;
            degv[i] = loc[j];
            cnt[i]  = run;           // cursor for fill
            run += (loc[j] + 15) & ~15;
        }
    }
}

__global__ __launch_bounds__(256) void k_fill(const int* __restrict__ ei, int* __restrict__ cursor,
                                              int* __restrict__ csr) {
    int e = blockIdx.x * 256 + threadIdx.x;
    if (e >= EE) return;
    int dst = ei[EE + e];
    int pos = atomicAdd(&cursor[dst], 1);
    csr[pos] = ei[e] << 7;            // byte offset of 128B fp16/bf16 row
}

// ---------------- weight prep: bf16, transposed [col][k]; q pre-scaled ----------------
__global__ __launch_bounds__(256) void k_wprep(const float* __restrict__ Wq, const float* __restrict__ Wk,
                                               const float* __restrict__ Wv, const float* __restrict__ Ws,
                                               const float* __restrict__ bq, const float* __restrict__ bk,
                                               const float* __restrict__ bv, const float* __restrict__ bs,
                                               unsigned short* __restrict__ wtb, float* __restrict__ bprep) {
    int idx = blockIdx.x * 256 + threadIdx.x;
    if (idx < LL * 4 * 64 * 64) {
        int l = idx >> 14; int j = (idx >> 12) & 3; int col = (idx >> 6) & 63; int k = idx & 63;
        const float* W = (j == 0 ? Wq : j == 1 ? Wk : j == 2 ? Wv : Ws) + l * 4096;
        float v = W[k * 64 + col];
        if (j == 0) v *= QSCL;
        wtb[idx] = f2bf(v);
    }
    if (idx < LL * 4 * 64) {
        int l = idx >> 8; int j = (idx >> 6) & 3; int c = idx & 63;
        const float* bsrc = (j == 0 ? bq : j == 1 ? bk : j == 2 ? bv : bs) + l * 64;
        bprep[idx] = bsrc[c] * (j == 0 ? QSCL : 1.0f);
    }
}

// ---------------- MFMA GEMM: one block per 64-row tile; wave w = matrix w ----------------
// w=0: qh (fp16, pre-scaled), w=1: kh (fp16), w=2: vb (bf16), w=3: h += skip
__global__ __launch_bounds__(256) void k_gemm(const unsigned short* __restrict__ hb,
                                              float* __restrict__ h,
                                              const unsigned short* __restrict__ wtb,   // + layer off
                                              const float* __restrict__ bprep,          // + layer off
                                              unsigned short* __restrict__ qh,
                                              unsigned short* __restrict__ kh,
                                              unsigned short* __restrict__ vb) {
    int tid = threadIdx.x;
    int l = tid & 63, w = tid >> 6;
    int row0 = blockIdx.x * 64;
    int colb = l & 15, kg = l >> 4;

    const unsigned short* wb = wtb + (size_t)w * 4096;   // [col][k]
    bf8_t bfr[2][4];
#pragma unroll
    for (int ks = 0; ks < 2; ++ks)
#pragma unroll
        for (int ct = 0; ct < 4; ++ct)
            bfr[ks][ct] = *(const bf8_t*)(wb + (ct * 16 + colb) * 64 + ks * 32 + kg * 8);

    bf8_t afr[2][4];
#pragma unroll
    for (int ks = 0; ks < 2; ++ks)
#pragma unroll
        for (int rt = 0; rt < 4; ++rt)
            afr[ks][rt] = *(const bf8_t*)(hb + (size_t)(row0 + rt * 16 + colb) * 64 + ks * 32 + kg * 8);

    f4_t acc[4][4];
#pragma unroll
    for (int rt = 0; rt < 4; ++rt)
#pragma unroll
        for (int ct = 0; ct < 4; ++ct)
            acc[rt][ct] = (f4_t){0.f, 0.f, 0.f, 0.f};
#pragma unroll
    for (int ks = 0; ks < 2; ++ks)
#pragma unroll
        for (int rt = 0; rt < 4; ++rt)
#pragma unroll
            for (int ct = 0; ct < 4; ++ct)
                acc[rt][ct] = __builtin_amdgcn_mfma_f32_16x16x32_bf16(afr[ks][rt], bfr[ks][ct],
                                                                      acc[rt][ct], 0, 0, 0);
    int rquad = l >> 4;     // D: col = l&15, row = rquad*4 + reg
#pragma unroll
    for (int ct = 0; ct < 4; ++ct) {
        int col = ct * 16 + colb;
        float bias = bprep[w * 64 + col];
#pragma unroll
        for (int rt = 0; rt < 4; ++rt)
#pragma unroll
            for (int r = 0; r < 4; ++r) {
                int row = row0 + rt * 16 + rquad * 4 + r;
                float val = acc[rt][ct][r] + bias;
                size_t off = (size_t)row * 64 + col;
                if      (w == 0) qh[off] = f2h(val);
                else if (w == 1) kh[off] = f2h(val);
                else if (w == 2) vb[off] = f2bf(val);
                else             h[off] += val;     // residual base = h + skip
            }
    }
}

// ---------------- fused attention gather + residual + layernorm (+ out proj on last) ----
// grid = 20000: b = bid&7 (XCD affinity; fp16/bf16 k+v per batch = 2.5MB fits 4MB L2)
// 16 edges/wave/iter: 4 per 16-lane group; Q/K fp16 dot2; DPP reductions
__global__ __launch_bounds__(256, 8) void k_attn_ln(const unsigned short* __restrict__ qh,
                                                    const unsigned short* __restrict__ kh,
                                                    const unsigned short* __restrict__ vb,
                                                    const int* __restrict__ rp,
                                                    const int* __restrict__ degv,
                                                    const int* __restrict__ csr,
                                                    const float* __restrict__ lng,
                                                    const float* __restrict__ lnb,
                                                    float* __restrict__ h,
                                                    unsigned short* __restrict__ hb,
                                                    const float* __restrict__ oW,   // null except last layer
                                                    const float* __restrict__ ob,
                                                    float* __restrict__ out) {
    int b    = blockIdx.x & 7;
    int n    = ((blockIdx.x >> 3) << 2) | __builtin_amdgcn_readfirstlane(threadIdx.x >> 6);
    int lane = threadIdx.x & 63;
    int lg   = lane & 15;       // channel block: channels 4*lg..4*lg+3, head = lg>>2
    int grp  = lane >> 4;       // edge sub-slot 0..3
    size_t wid = (size_t)b * NN + n;

    const char* kbase = (const char*)kh + (size_t)b * NN * 128;   // wave-uniform
    const char* vbase = (const char*)vb + (size_t)b * NN * 128;
    int lgoff = lg * 8;

    uint2 qp = ((const uint2*)qh)[wid * 16 + lg];   // 4 fp16 (pre-scaled, log2 domain)

    int e0 = rp[n], deg = degv[n];
    int e1 = e0 + deg;
    float den0 = 0.f, den1 = 0.f;
    float4 av0 = {0.f, 0.f, 0.f, 0.f}, av1 = {0.f, 0.f, 0.f, 0.f};

    for (int e = e0; e < e1; e += 16) {
        // 4 edges per 16-lane group; padded-to-16 lists keep all csr reads in-bounds
        int c0 = csr[e + grp];
        int c1 = csr[e + 4 + grp];
        int c2 = csr[e + 8 + grp];
        int c3 = csr[e + 12 + grp];
        unsigned o0 = (unsigned)(c0 + lgoff), o1 = (unsigned)(c1 + lgoff);
        unsigned o2 = (unsigned)(c2 + lgoff), o3 = (unsigned)(c3 + lgoff);
        uint2 k0 = *(const uint2*)(kbase + o0);
        uint2 k1 = *(const uint2*)(kbase + o1);
        uint2 k2 = *(const uint2*)(kbase + o2);
        uint2 k3 = *(const uint2*)(kbase + o3);
        ushort4 v0 = *(const ushort4*)(vbase + o0);
        ushort4 v1 = *(const ushort4*)(vbase + o1);
        ushort4 v2 = *(const ushort4*)(vbase + o2);
        ushort4 v3 = *(const ushort4*)(vbase + o3);

        float m0 = (e + grp      < e1) ? 1.f : 0.f;
        float m1 = (e + 4 + grp  < e1) ? 1.f : 0.f;
        float m2 = (e + 8 + grp  < e1) ? 1.f : 0.f;
        float m3 = (e + 12 + grp < e1) ? 1.f : 0.f;

        // per-lane 4-channel partial via packed dot2, then quad reduce (DPP)
        float d0 = dot2(k0.y, qp.y, dot2(k0.x, qp.x, 0.f));
        float d1 = dot2(k1.y, qp.y, dot2(k1.x, qp.x, 0.f));
        float d2 = dot2(k2.y, qp.y, dot2(k2.x, qp.x, 0.f));
        float d3 = dot2(k3.y, qp.y, dot2(k3.x, qp.x, 0.f));
        d0 = quad_sum(d0); d1 = quad_sum(d1);
        d2 = quad_sum(d2); d3 = quad_sum(d3);

        float w0 = m0 * __builtin_amdgcn_exp2f(d0);
        float w1 = m1 * __builtin_amdgcn_exp2f(d1);
        float w2 = m2 * __builtin_amdgcn_exp2f(d2);
        float w3 = m3 * __builtin_amdgcn_exp2f(d3);

        den0 += w0 + w1;
        den1 += w2 + w3;
        av0.x += w0 * bf2f(v0.x) + w1 * bf2f(v1.x);
        av0.y += w0 * bf2f(v0.y) + w1 * bf2f(v1.y);
        av0.z += w0 * bf2f(v0.z) + w1 * bf2f(v1.z);
        av0.w += w0 * bf2f(v0.w) + w1 * bf2f(v1.w);
        av1.x += w2 * bf2f(v2.x) + w3 * bf2f(v3.x);
        av1.y += w2 * bf2f(v2.y) + w3 * bf2f(v3.y);
        av1.z += w2 * bf2f(v2.z) + w3 * bf2f(v3.z);
        av1.w += w2 * bf2f(v2.w) + w3 * bf2f(v3.w);
    }

    float den = den0 + den1;
    float4 av = {av0.x + av1.x, av0.y + av1.y, av0.z + av1.z, av0.w + av1.w};

    // merge the 4 edge-groups: pure sums (shared softmax reference m=0)
#pragma unroll
    for (int off = 16; off <= 32; off <<= 1) {
        den  += __shfl_xor(den, off);
        av.x += __shfl_xor(av.x, off); av.y += __shfl_xor(av.y, off);
        av.z += __shfl_xor(av.z, off); av.w += __shfl_xor(av.w, off);
    }
    float inv = (den > 0.f) ? __builtin_amdgcn_rcpf(den) : 0.f;

    // residual (h already holds h + skip) + layernorm (DPP 16-lane sums)
    float4 h4 = ((const float4*)h)[wid * 16 + lg];
    float4 x4;
    x4.x = h4.x + av.x * inv; x4.y = h4.y + av.y * inv;
    x4.z = h4.z + av.z * inv; x4.w = h4.w + av.w * inv;

    float s = row_sum(x4.x + x4.y + x4.z + x4.w);
    float mu = s * (1.f / 64.f);
    float4 dx;
    dx.x = x4.x - mu; dx.y = x4.y - mu; dx.z = x4.z - mu; dx.w = x4.w - mu;
    float vs = row_sum(dx.x * dx.x + dx.y * dx.y + dx.z * dx.z + dx.w * dx.w);
    float r = __builtin_amdgcn_rsqf(vs * (1.f / 64.f) + 1e-5f);

    float4 g4 = ((const float4*)lng)[lg];
    float4 b4 = ((const float4*)lnb)[lg];
    float4 o4;
    o4.x = dx.x * r * g4.x + b4.x; o4.y = dx.y * r * g4.y + b4.y;
    o4.z = dx.z * r * g4.z + b4.z; o4.w = dx.w * r * g4.w + b4.w;

    if (oW) {
        // fused output projection: t_p = sum_c o4[c] * oW[c][p]; DPP row reduce
        int c0 = lg * 4;
        float t0 = o4.x * oW[(c0+0)*3+0] + o4.y * oW[(c0+1)*3+0] + o4.z * oW[(c0+2)*3+0] + o4.w * oW[(c0+3)*3+0];
        float t1 = o4.x * oW[(c0+0)*3+1] + o4.y * oW[(c0+1)*3+1] + o4.z * oW[(c0+2)*3+1] + o4.w * oW[(c0+3)*3+1];
        float t2 = o4.x * oW[(c0+0)*3+2] + o4.y * oW[(c0+1)*3+2] + o4.z * oW[(c0+2)*3+2] + o4.w * oW[(c0+3)*3+2];
        t0 = row_sum(t0); t1 = row_sum(t1); t2 = row_sum(t2);
        if (lane == 0) {
            out[((size_t)b * PP + 0) * NN + n] = t0 + ob[0];
            out[((size_t)b * PP + 1) * NN + n] = t1 + ob[1];
            out[((size_t)b * PP + 2) * NN + n] = t2 + ob[2];
        }
    } else if (lane < 16) {
        ((float4*)h)[wid * 16 + lg] = o4;
        ushort4 hu = {f2bf(o4.x), f2bf(o4.y), f2bf(o4.z), f2bf(o4.w)};
        ((ushort4*)hb)[wid * 16 + lg] = hu;
    }
}

extern "C" void kernel_launch(void* const* d_in, const int* in_sizes, int n_in,
                              void* d_out, int out_size, void* d_ws, size_t ws_size,
                              hipStream_t stream) {
    const float* x    = (const float*)d_in[0];
    const int*   ei   = (const int*)  d_in[1];
    const float* inW  = (const float*)d_in[2];
    const float* inb  = (const float*)d_in[3];
    const float* Wq   = (const float*)d_in[4];
    const float* bq   = (const float*)d_in[5];
    const float* Wk   = (const float*)d_in[6];
    const float* bk   = (const float*)d_in[7];
    const float* Wv   = (const float*)d_in[8];
    const float* bv   = (const float*)d_in[9];
    const float* Wsk  = (const float*)d_in[10];
    const float* bsk  = (const float*)d_in[11];
    const float* lng  = (const float*)d_in[12];
    const float* lnb  = (const float*)d_in[13];
    const float* outW = (const float*)d_in[14];
    const float* outb = (const float*)d_in[15];
    float* out = (float*)d_out;

    float* h    = (float*)d_ws;                                       // BN*64 f32
    unsigned short* hb = (unsigned short*)(h + (size_t)BN * 64);      // BN*64 bf16
    unsigned short* qh = hb + (size_t)BN * 64;                        // BN*64 fp16
    unsigned short* kh = qh + (size_t)BN * 64;                        // BN*64 fp16
    unsigned short* vb = kh + (size_t)BN * 64;                        // BN*64 bf16
    int* rp      = (int*)(vb + (size_t)BN * 64);
    int* degv    = rp + NN;
    int* cursor  = degv + NN;
    int* csr     = cursor + NN;                          // CSR_CAP entries
    unsigned short* wtb = (unsigned short*)(csr + CSR_CAP);  // LL*4*64*64 bf16
    float* bprep = (float*)(wtb + LL * 4 * 64 * 64);         // LL*4*64 f32

    // CSR build + weight prep (edge list/weights constant across layers/batches)
    hipMemsetAsync(cursor, 0, (NN + CSR_CAP) * sizeof(int), stream);   // cursor + csr
    k_count<<<(EE + 255) / 256, 256, 0, stream>>>(ei, cursor);
    k_scan <<<1, 1024, 0, stream>>>(cursor, rp, degv);
    k_fill <<<(EE + 255) / 256, 256, 0, stream>>>(ei, cursor, csr);
    k_wprep<<<(LL * 4 * 64 * 64 + 255) / 256, 256, 0, stream>>>(Wq, Wk, Wv, Wsk, bq, bk, bv, bsk,
                                                                wtb, bprep);

    k_input_proj<<<(BN * 64 + 255) / 256, 256, 0, stream>>>(x, inW, inb, h, hb);

    for (int l = 0; l < LL; ++l) {
        k_gemm<<<BN / 64, 256, 0, stream>>>(hb, h, wtb + (size_t)l * 4 * 4096,
                                            bprep + (size_t)l * 4 * 64, qh, kh, vb);
        k_attn_ln<<<BN / 4, 256, 0, stream>>>(qh, kh, vb, rp, degv, csr,
                                              lng, lnb, h, hb,
                                              (l == LL - 1) ? outW : nullptr, outb, out);
    }
}

// Round 8
// 347.036 us; speedup vs baseline: 1.3084x; 1.2149x over previous
//
#include <hip/hip_runtime.h>
#include <hip/hip_bf16.h>
#include <math.h>

#define NN 10000      // nodes
#define EE 320000     // edges
#define BB 8          // batch
#define SS 12         // seq
#define PP 3          // pred
#define LL 3          // layers
#define BN (BB*NN)    // 80000 rows
#define CSR_CAP (EE + 16*NN + 64)    // padded-to-16 lists + slack
#define QSCL (0.25f * 1.44269504f)   // 1/sqrt(16) * log2(e)  -> exp2 domain

typedef __attribute__((ext_vector_type(8))) short bf8_t;   // 8 bf16 (4 VGPR)
typedef __attribute__((ext_vector_type(4))) float f4_t;

__device__ __forceinline__ float bf2f(unsigned short u) {
    unsigned int x = ((unsigned int)u) << 16;
    return __builtin_bit_cast(float, x);
}
__device__ __forceinline__ unsigned short f2bf(float f) {
    unsigned int u = __builtin_bit_cast(unsigned int, f);
    u += 0x7FFF + ((u >> 16) & 1);           // RNE
    return (unsigned short)(u >> 16);
}
__device__ __forceinline__ unsigned short f2h(float f) {
    _Float16 h = (_Float16)f;
    return __builtin_bit_cast(unsigned short, h);
}
// v_dot2_f32_f16: d = a.h0*b.h0 + a.h1*b.h1 + c   (packed half2 in 32-bit regs)
__device__ __forceinline__ float dot2(unsigned a, unsigned b, float c) {
    float d;
    asm("v_dot2_f32_f16 %0, %1, %2, %3" : "=v"(d) : "v"(a), "v"(b), "v"(c));
    return d;
}
// DPP add-reduce helpers (pure VALU; bound_ctrl=1)
template<int CTRL>
__device__ __forceinline__ float dppadd(float x) {
    int t = __builtin_amdgcn_update_dpp(0, __builtin_bit_cast(int, x), CTRL, 0xF, 0xF, true);
    return x + __builtin_bit_cast(float, t);
}
#define QX1 0xB1   // quad_perm [1,0,3,2]  == xor1
#define QX2 0x4E   // quad_perm [2,3,0,1]  == xor2
#define RR4 0x124  // row_ror:4
#define RR8 0x128  // row_ror:8
__device__ __forceinline__ float quad_sum(float x) {         // sum over 4 quad lanes
    x = dppadd<QX1>(x); x = dppadd<QX2>(x); return x;
}
__device__ __forceinline__ float row_sum(float x) {          // sum over 16-lane row
    x = dppadd<QX1>(x); x = dppadd<QX2>(x);
    x = dppadd<RR4>(x); x = dppadd<RR8>(x); return x;
}

// ---------------- CSR count + weight prep (merged; independent work) ----------------
__global__ __launch_bounds__(256) void k_count(const int* __restrict__ ei, int* __restrict__ cnt,
                                               const float* __restrict__ Wq, const float* __restrict__ Wk,
                                               const float* __restrict__ Wv, const float* __restrict__ Ws,
                                               const float* __restrict__ bq, const float* __restrict__ bk,
                                               const float* __restrict__ bv, const float* __restrict__ bs,
                                               unsigned short* __restrict__ wtb, float* __restrict__ bprep) {
    int e = blockIdx.x * 256 + threadIdx.x;
    if (e < EE) atomicAdd(&cnt[ei[EE + e]], 1);   // dst
    if (e < LL * 4 * 64 * 64) {
        int l = e >> 14; int j = (e >> 12) & 3; int col = (e >> 6) & 63; int k = e & 63;
        const float* W = (j == 0 ? Wq : j == 1 ? Wk : j == 2 ? Wv : Ws) + l * 4096;
        float v = W[k * 64 + col];
        if (j == 0) v *= QSCL;
        wtb[e] = f2bf(v);
    }
    if (e < LL * 4 * 64) {
        int l = e >> 8; int j = (e >> 6) & 3; int c = e & 63;
        const float* bsrc = (j == 0 ? bq : j == 1 ? bk : j == 2 ? bv : bs) + l * 64;
        bprep[e] = bsrc[c] * (j == 0 ? QSCL : 1.0f);
    }
}

// single block, 1024 threads, 10 nodes/thread serial + one block scan.
// outputs: rp[n] = padded start (pad-16), degv[n] = real degree, cursor[n] = rp[n]
__global__ __launch_bounds__(1024) void k_scan(int* __restrict__ cnt,      // in: counts (== cursor buf)
                                               int* __restrict__ rp,
                                               int* __restrict__ degv) {
    __shared__ int ssum[1024];
    int t = threadIdx.x;
    int base = t * 10;
    int loc[10];
    int s = 0;
#pragma unroll
    for (int j = 0; j < 10; ++j) {
        int i = base + j;
        int d = (i < NN) ? cnt[i] : 0;
        loc[j] = d;
        s += (d + 15) & ~15;
    }
    ssum[t] = s;
    __syncthreads();
    for (int off = 1; off < 1024; off <<= 1) {
        int v = (t >= off) ? ssum[t - off] : 0;
        __syncthreads();
        ssum[t] += v;
        __syncthreads();
    }
    int run = ssum[t] - s;   // exclusive prefix of padded sizes
#pragma unroll
    for (int j = 0; j < 10; ++j) {
        int i = base + j;
        if (i < NN) {
            rp[i]   = run;
            degv[i] = loc[j];
            cnt[i]  = run;           // cursor for fill
            run += (loc[j] + 15) & ~15;
        }
    }
}

__global__ __launch_bounds__(256) void k_fill(const int* __restrict__ ei, int* __restrict__ cursor,
                                              int* __restrict__ csr) {
    int e = blockIdx.x * 256 + threadIdx.x;
    if (e >= EE) return;
    int dst = ei[EE + e];
    int pos = atomicAdd(&cursor[dst], 1);
    csr[pos] = ei[e] << 7;            // byte offset of 128B fp16/bf16 row
}

// ---------------- MFMA GEMM (swapped operands): one block per 64-row tile ----------------
// wave w: w=0 qh (fp16, pre-scaled), w=1 kh (fp16), w=2 vb (bf16), w=3 h += skip.
// A = weight frag [col][k], B = h frag [row][k]  =>  D: lane&15 = ROW, (lane>>4)*4+reg = COL
// => each lane stores 4 CONTIGUOUS cols per (rt,ct): vectorized ushort4/float4 epilogue.
// first!=0: compute input projection for this block's 64 rows before the GEMM.
__global__ __launch_bounds__(256, 4) void k_gemm(const float* __restrict__ x,
                                                 const float* __restrict__ inW,
                                                 const float* __restrict__ inb,
                                                 int first,
                                                 unsigned short* hb,
                                                 float* h,
                                                 const unsigned short* __restrict__ wtb,   // + layer off
                                                 const float* __restrict__ bprep,          // + layer off
                                                 unsigned short* __restrict__ qh,
                                                 unsigned short* __restrict__ kh,
                                                 unsigned short* __restrict__ vb) {
    int tid = threadIdx.x;
    int l = tid & 63, w = tid >> 6;
    int row0 = blockIdx.x * 64;
    int colb = l & 15, kg = l >> 4, rquad = kg;

    if (first) {
        int c = tid & 63;
        int rb = tid >> 6;
        for (int j = 0; j < 16; ++j) {
            int row = row0 + rb + j * 4;
            int b = row / NN;
            int n = row - b * NN;
            float s = inb[c];
#pragma unroll
            for (int t = 0; t < SS; ++t)
                s += x[((size_t)b * SS + t) * NN + n] * inW[t * 64 + c];
            h[(size_t)row * 64 + c]  = s;
            hb[(size_t)row * 64 + c] = f2bf(s);
        }
        __syncthreads();
    }

    const unsigned short* wb = wtb + (size_t)w * 4096;   // [col][k]
    bf8_t wfr[2][4];
#pragma unroll
    for (int ks = 0; ks < 2; ++ks)
#pragma unroll
        for (int ct = 0; ct < 4; ++ct)
            wfr[ks][ct] = *(const bf8_t*)(wb + (ct * 16 + colb) * 64 + ks * 32 + kg * 8);
    float4 biasv[4];
#pragma unroll
    for (int ct = 0; ct < 4; ++ct)
        biasv[ct] = *(const float4*)(bprep + w * 64 + ct * 16 + rquad * 4);

#pragma unroll
    for (int rt = 0; rt < 4; ++rt) {
        bf8_t hfr[2];
#pragma unroll
        for (int ks = 0; ks < 2; ++ks)
            hfr[ks] = *(const bf8_t*)(hb + (size_t)(row0 + rt * 16 + colb) * 64 + ks * 32 + kg * 8);
        f4_t acc[4];
#pragma unroll
        for (int ct = 0; ct < 4; ++ct) acc[ct] = (f4_t){0.f, 0.f, 0.f, 0.f};
#pragma unroll
        for (int ks = 0; ks < 2; ++ks)
#pragma unroll
            for (int ct = 0; ct < 4; ++ct)
                acc[ct] = __builtin_amdgcn_mfma_f32_16x16x32_bf16(wfr[ks][ct], hfr[ks], acc[ct], 0, 0, 0);

        size_t rowoff = (size_t)(row0 + rt * 16 + colb) * 64;   // lane's row
#pragma unroll
        for (int ct = 0; ct < 4; ++ct) {
            int c0 = ct * 16 + rquad * 4;
            float v0 = acc[ct][0] + biasv[ct].x;
            float v1 = acc[ct][1] + biasv[ct].y;
            float v2 = acc[ct][2] + biasv[ct].z;
            float v3 = acc[ct][3] + biasv[ct].w;
            if (w == 0) {
                ushort4 st = {f2h(v0), f2h(v1), f2h(v2), f2h(v3)};
                *(ushort4*)(qh + rowoff + c0) = st;
            } else if (w == 1) {
                ushort4 st = {f2h(v0), f2h(v1), f2h(v2), f2h(v3)};
                *(ushort4*)(kh + rowoff + c0) = st;
            } else if (w == 2) {
                ushort4 st = {f2bf(v0), f2bf(v1), f2bf(v2), f2bf(v3)};
                *(ushort4*)(vb + rowoff + c0) = st;
            } else {
                float4 hv = *(float4*)(h + rowoff + c0);
                hv.x += v0; hv.y += v1; hv.z += v2; hv.w += v3;
                *(float4*)(h + rowoff + c0) = hv;     // residual base = h + skip
            }
        }
    }
}

// ---------------- fused attention gather + residual + layernorm (+ out proj on last) ----
// grid = 20000: b = bid&7 (XCD affinity; fp16/bf16 k+v per batch = 2.5MB fits 4MB L2)
// 16 edges/wave/iter: full iters unmasked + one masked tail; Q/K fp16 dot2; DPP reductions
__global__ __launch_bounds__(256, 8) void k_attn_ln(const unsigned short* __restrict__ qh,
                                                    const unsigned short* __restrict__ kh,
                                                    const unsigned short* __restrict__ vb,
                                                    const int* __restrict__ rp,
                                                    const int* __restrict__ degv,
                                                    const int* __restrict__ csr,
                                                    const float* __restrict__ lng,
                                                    const float* __restrict__ lnb,
                                                    float* __restrict__ h,
                                                    unsigned short* __restrict__ hb,
                                                    const float* __restrict__ oW,   // null except last layer
                                                    const float* __restrict__ ob,
                                                    float* __restrict__ out) {
    int b    = blockIdx.x & 7;
    int n    = ((blockIdx.x >> 3) << 2) | __builtin_amdgcn_readfirstlane(threadIdx.x >> 6);
    int lane = threadIdx.x & 63;
    int lg   = lane & 15;       // channel block: channels 4*lg..4*lg+3, head = lg>>2
    int grp  = lane >> 4;       // edge sub-slot 0..3
    size_t wid = (size_t)b * NN + n;

    const char* kbase = (const char*)kh + (size_t)b * NN * 128;   // wave-uniform
    const char* vbase = (const char*)vb + (size_t)b * NN * 128;
    int lgoff = lg * 8;

    uint2 qp = ((const uint2*)qh)[wid * 16 + lg];   // 4 fp16 (pre-scaled, log2 domain)

    int e0 = rp[n], deg = degv[n];
    int nf  = deg >> 4;         // full 16-edge chunks
    int rem = deg & 15;
    float den0 = 0.f, den1 = 0.f;
    float4 av0 = {0.f, 0.f, 0.f, 0.f}, av1 = {0.f, 0.f, 0.f, 0.f};

    int e = e0;
    for (int f = 0; f < nf; ++f, e += 16) {
        int c0 = csr[e + grp];
        int c1 = csr[e + 4 + grp];
        int c2 = csr[e + 8 + grp];
        int c3 = csr[e + 12 + grp];
        unsigned o0 = (unsigned)(c0 + lgoff), o1 = (unsigned)(c1 + lgoff);
        unsigned o2 = (unsigned)(c2 + lgoff), o3 = (unsigned)(c3 + lgoff);
        uint2 k0 = *(const uint2*)(kbase + o0);
        uint2 k1 = *(const uint2*)(kbase + o1);
        uint2 k2 = *(const uint2*)(kbase + o2);
        uint2 k3 = *(const uint2*)(kbase + o3);
        ushort4 v0 = *(const ushort4*)(vbase + o0);
        ushort4 v1 = *(const ushort4*)(vbase + o1);
        ushort4 v2 = *(const ushort4*)(vbase + o2);
        ushort4 v3 = *(const ushort4*)(vbase + o3);

        float d0 = dot2(k0.y, qp.y, dot2(k0.x, qp.x, 0.f));
        float d1 = dot2(k1.y, qp.y, dot2(k1.x, qp.x, 0.f));
        float d2 = dot2(k2.y, qp.y, dot2(k2.x, qp.x, 0.f));
        float d3 = dot2(k3.y, qp.y, dot2(k3.x, qp.x, 0.f));
        d0 = quad_sum(d0); d1 = quad_sum(d1);
        d2 = quad_sum(d2); d3 = quad_sum(d3);

        float w0 = __builtin_amdgcn_exp2f(d0);
        float w1 = __builtin_amdgcn_exp2f(d1);
        float w2 = __builtin_amdgcn_exp2f(d2);
        float w3 = __builtin_amdgcn_exp2f(d3);

        den0 += w0 + w1;
        den1 += w2 + w3;
        av0.x += w0 * bf2f(v0.x) + w1 * bf2f(v1.x);
        av0.y += w0 * bf2f(v0.y) + w1 * bf2f(v1.y);
        av0.z += w0 * bf2f(v0.z) + w1 * bf2f(v1.z);
        av0.w += w0 * bf2f(v0.w) + w1 * bf2f(v1.w);
        av1.x += w2 * bf2f(v2.x) + w3 * bf2f(v3.x);
        av1.y += w2 * bf2f(v2.y) + w3 * bf2f(v3.y);
        av1.z += w2 * bf2f(v2.z) + w3 * bf2f(v3.z);
        av1.w += w2 * bf2f(v2.w) + w3 * bf2f(v3.w);
    }
    if (rem) {
        int c0 = csr[e + grp];
        int c1 = csr[e + 4 + grp];
        int c2 = csr[e + 8 + grp];
        int c3 = csr[e + 12 + grp];
        unsigned o0 = (unsigned)(c0 + lgoff), o1 = (unsigned)(c1 + lgoff);
        unsigned o2 = (unsigned)(c2 + lgoff), o3 = (unsigned)(c3 + lgoff);
        uint2 k0 = *(const uint2*)(kbase + o0);
        uint2 k1 = *(const uint2*)(kbase + o1);
        uint2 k2 = *(const uint2*)(kbase + o2);
        uint2 k3 = *(const uint2*)(kbase + o3);
        ushort4 v0 = *(const ushort4*)(vbase + o0);
        ushort4 v1 = *(const ushort4*)(vbase + o1);
        ushort4 v2 = *(const ushort4*)(vbase + o2);
        ushort4 v3 = *(const ushort4*)(vbase + o3);

        float m0 = (grp      < rem) ? 1.f : 0.f;
        float m1 = (grp + 4  < rem) ? 1.f : 0.f;
        float m2 = (grp + 8  < rem) ? 1.f : 0.f;
        float m3 = (grp + 12 < rem) ? 1.f : 0.f;

        float d0 = dot2(k0.y, qp.y, dot2(k0.x, qp.x, 0.f));
        float d1 = dot2(k1.y, qp.y, dot2(k1.x, qp.x, 0.f));
        float d2 = dot2(k2.y, qp.y, dot2(k2.x, qp.x, 0.f));
        float d3 = dot2(k3.y, qp.y, dot2(k3.x, qp.x, 0.f));
        d0 = quad_sum(d0); d1 = quad_sum(d1);
        d2 = quad_sum(d2); d3 = quad_sum(d3);

        float w0 = m0 * __builtin_amdgcn_exp2f(d0);
        float w1 = m1 * __builtin_amdgcn_exp2f(d1);
        float w2 = m2 * __builtin_amdgcn_exp2f(d2);
        float w3 = m3 * __builtin_amdgcn_exp2f(d3);

        den0 += w0 + w1;
        den1 += w2 + w3;
        av0.x += w0 * bf2f(v0.x) + w1 * bf2f(v1.x);
        av0.y += w0 * bf2f(v0.y) + w1 * bf2f(v1.y);
        av0.z += w0 * bf2f(v0.z) + w1 * bf2f(v1.z);
        av0.w += w0 * bf2f(v0.w) + w1 * bf2f(v1.w);
        av1.x += w2 * bf2f(v2.x) + w3 * bf2f(v3.x);
        av1.y += w2 * bf2f(v2.y) + w3 * bf2f(v3.y);
        av1.z += w2 * bf2f(v2.z) + w3 * bf2f(v3.z);
        av1.w += w2 * bf2f(v2.w) + w3 * bf2f(v3.w);
    }

    float den = den0 + den1;
    float4 av = {av0.x + av1.x, av0.y + av1.y, av0.z + av1.z, av0.w + av1.w};

    // merge the 4 edge-groups: pure sums (shared softmax reference m=0)
#pragma unroll
    for (int off = 16; off <= 32; off <<= 1) {
        den  += __shfl_xor(den, off);
        av.x += __shfl_xor(av.x, off); av.y += __shfl_xor(av.y, off);
        av.z += __shfl_xor(av.z, off); av.w += __shfl_xor(av.w, off);
    }
    float inv = (den > 0.f) ? __builtin_amdgcn_rcpf(den) : 0.f;

    // residual (h already holds h + skip) + layernorm (DPP 16-lane sums)
    float4 h4 = ((const float4*)h)[wid * 16 + lg];
    float4 x4;
    x4.x = h4.x + av.x * inv; x4.y = h4.y + av.y * inv;
    x4.z = h4.z + av.z * inv; x4.w = h4.w + av.w * inv;

    float s = row_sum(x4.x + x4.y + x4.z + x4.w);
    float mu = s * (1.f / 64.f);
    float4 dx;
    dx.x = x4.x - mu; dx.y = x4.y - mu; dx.z = x4.z - mu; dx.w = x4.w - mu;
    float vs = row_sum(dx.x * dx.x + dx.y * dx.y + dx.z * dx.z + dx.w * dx.w);
    float r = __builtin_amdgcn_rsqf(vs * (1.f / 64.f) + 1e-5f);

    float4 g4 = ((const float4*)lng)[lg];
    float4 b4 = ((const float4*)lnb)[lg];
    float4 o4;
    o4.x = dx.x * r * g4.x + b4.x; o4.y = dx.y * r * g4.y + b4.y;
    o4.z = dx.z * r * g4.z + b4.z; o4.w = dx.w * r * g4.w + b4.w;

    if (oW) {
        // fused output projection: t_p = sum_c o4[c] * oW[c][p]; DPP row reduce
        int c0 = lg * 4;
        float t0 = o4.x * oW[(c0+0)*3+0] + o4.y * oW[(c0+1)*3+0] + o4.z * oW[(c0+2)*3+0] + o4.w * oW[(c0+3)*3+0];
        float t1 = o4.x * oW[(c0+0)*3+1] + o4.y * oW[(c0+1)*3+1] + o4.z * oW[(c0+2)*3+1] + o4.w * oW[(c0+3)*3+1];
        float t2 = o4.x * oW[(c0+0)*3+2] + o4.y * oW[(c0+1)*3+2] + o4.z * oW[(c0+2)*3+2] + o4.w * oW[(c0+3)*3+2];
        t0 = row_sum(t0); t1 = row_sum(t1); t2 = row_sum(t2);
        if (lane == 0) {
            out[((size_t)b * PP + 0) * NN + n] = t0 + ob[0];
            out[((size_t)b * PP + 1) * NN + n] = t1 + ob[1];
            out[((size_t)b * PP + 2) * NN + n] = t2 + ob[2];
        }
    } else if (lane < 16) {
        ((float4*)h)[wid * 16 + lg] = o4;
        ushort4 hu = {f2bf(o4.x), f2bf(o4.y), f2bf(o4.z), f2bf(o4.w)};
        ((ushort4*)hb)[wid * 16 + lg] = hu;
    }
}

extern "C" void kernel_launch(void* const* d_in, const int* in_sizes, int n_in,
                              void* d_out, int out_size, void* d_ws, size_t ws_size,
                              hipStream_t stream) {
    const float* x    = (const float*)d_in[0];
    const int*   ei   = (const int*)  d_in[1];
    const float* inW  = (const float*)d_in[2];
    const float* inb  = (const float*)d_in[3];
    const float* Wq   = (const float*)d_in[4];
    const float* bq   = (const float*)d_in[5];
    const float* Wk   = (const float*)d_in[6];
    const float* bk   = (const float*)d_in[7];
    const float* Wv   = (const float*)d_in[8];
    const float* bv   = (const float*)d_in[9];
    const float* Wsk  = (const float*)d_in[10];
    const float* bsk  = (const float*)d_in[11];
    const float* lng  = (const float*)d_in[12];
    const float* lnb  = (const float*)d_in[13];
    const float* outW = (const float*)d_in[14];
    const float* outb = (const float*)d_in[15];
    float* out = (float*)d_out;

    float* h    = (float*)d_ws;                                       // BN*64 f32
    unsigned short* hb = (unsigned short*)(h + (size_t)BN * 64);      // BN*64 bf16
    unsigned short* qh = hb + (size_t)BN * 64;                        // BN*64 fp16
    unsigned short* kh = qh + (size_t)BN * 64;                        // BN*64 fp16
    unsigned short* vb = kh + (size_t)BN * 64;                        // BN*64 bf16
    int* rp      = (int*)(vb + (size_t)BN * 64);
    int* degv    = rp + NN;
    int* cursor  = degv + NN;
    int* csr     = cursor + NN;                          // CSR_CAP entries
    unsigned short* wtb = (unsigned short*)(csr + CSR_CAP);  // LL*4*64*64 bf16
    float* bprep = (float*)(wtb + LL * 4 * 64 * 64);         // LL*4*64 f32

    // CSR build + weight prep (edge list/weights constant across layers/batches)
    hipMemsetAsync(cursor, 0, (NN + CSR_CAP) * sizeof(int), stream);   // cursor + csr
    k_count<<<(EE + 255) / 256, 256, 0, stream>>>(ei, cursor, Wq, Wk, Wv, Wsk,
                                                  bq, bk, bv, bsk, wtb, bprep);
    k_scan <<<1, 1024, 0, stream>>>(cursor, rp, degv);
    k_fill <<<(EE + 255) / 256, 256, 0, stream>>>(ei, cursor, csr);

    for (int l = 0; l < LL; ++l) {
        k_gemm<<<BN / 64, 256, 0, stream>>>(x, inW, inb, (l == 0) ? 1 : 0, hb, h,
                                            wtb + (size_t)l * 4 * 4096,
                                            bprep + (size_t)l * 4 * 64, qh, kh, vb);
        k_attn_ln<<<BN / 4, 256, 0, stream>>>(qh, kh, vb, rp, degv, csr,
                                              lng, lnb, h, hb,
                                              (l == LL - 1) ? outW : nullptr, outb, out);
    }
}

// Round 9
// 286.493 us; speedup vs baseline: 1.5849x; 1.2113x over previous
//
#include <hip/hip_runtime.h>
#include <hip/hip_bf16.h>
#include <math.h>

#define NN 10000      // nodes
#define EE 320000     // edges
#define BB 8          // batch
#define SS 12         // seq
#define PP 3          // pred
#define LL 3          // layers
#define BN (BB*NN)    // 80000 rows
#define CSR_CAP (EE + 16*NN + 64)    // padded-to-16 lists + slack
#define QSCL (0.25f * 1.44269504f)   // 1/sqrt(16) * log2(e)  -> exp2 domain

typedef __attribute__((ext_vector_type(8))) short bf8_t;   // 8 bf16 (4 VGPR)
typedef __attribute__((ext_vector_type(4))) float f4_t;

__device__ __forceinline__ float bf2f(unsigned short u) {
    unsigned int x = ((unsigned int)u) << 16;
    return __builtin_bit_cast(float, x);
}
__device__ __forceinline__ unsigned short f2bf(float f) {
    unsigned int u = __builtin_bit_cast(unsigned int, f);
    u += 0x7FFF + ((u >> 16) & 1);           // RNE
    return (unsigned short)(u >> 16);
}
__device__ __forceinline__ unsigned short f2h(float f) {
    _Float16 h = (_Float16)f;
    return __builtin_bit_cast(unsigned short, h);
}
// v_dot2_f32_f16: d = a.h0*b.h0 + a.h1*b.h1 + c   (packed half2 in 32-bit regs)
__device__ __forceinline__ float dot2(unsigned a, unsigned b, float c) {
    float d;
    asm("v_dot2_f32_f16 %0, %1, %2, %3" : "=v"(d) : "v"(a), "v"(b), "v"(c));
    return d;
}
// v_fma_mix_f32: f32 accum from packed-fp16 operand (lo/hi half of src0)
__device__ __forceinline__ float fma_mixlo(unsigned v, float w, float acc) {
    float d;
    asm("v_fma_mix_f32 %0, %1, %2, %3 op_sel_hi:[1,0,0]"
        : "=v"(d) : "v"(v), "v"(w), "v"(acc));
    return d;
}
__device__ __forceinline__ float fma_mixhi(unsigned v, float w, float acc) {
    float d;
    asm("v_fma_mix_f32 %0, %1, %2, %3 op_sel:[1,0,0] op_sel_hi:[1,0,0]"
        : "=v"(d) : "v"(v), "v"(w), "v"(acc));
    return d;
}
// DPP add-reduce helpers (pure VALU; bound_ctrl=1)
template<int CTRL>
__device__ __forceinline__ float dppadd(float x) {
    int t = __builtin_amdgcn_update_dpp(0, __builtin_bit_cast(int, x), CTRL, 0xF, 0xF, true);
    return x + __builtin_bit_cast(float, t);
}
#define QX1 0xB1   // quad_perm [1,0,3,2]  == xor1
#define QX2 0x4E   // quad_perm [2,3,0,1]  == xor2
#define RR4 0x124  // row_ror:4
#define RR8 0x128  // row_ror:8
__device__ __forceinline__ float quad_sum(float x) {         // sum over 4 quad lanes
    x = dppadd<QX1>(x); x = dppadd<QX2>(x); return x;
}
__device__ __forceinline__ float row_sum(float x) {          // sum over 16-lane row
    x = dppadd<QX1>(x); x = dppadd<QX2>(x);
    x = dppadd<RR4>(x); x = dppadd<RR8>(x); return x;
}

// ---------------- CSR count + weight prep (merged; independent work) ----------------
__global__ __launch_bounds__(256) void k_count(const int* __restrict__ ei, int* __restrict__ cnt,
                                               const float* __restrict__ Wq, const float* __restrict__ Wk,
                                               const float* __restrict__ Wv, const float* __restrict__ Ws,
                                               const float* __restrict__ bq, const float* __restrict__ bk,
                                               const float* __restrict__ bv, const float* __restrict__ bs,
                                               unsigned short* __restrict__ wtb, float* __restrict__ bprep) {
    int e = blockIdx.x * 256 + threadIdx.x;
    if (e < EE) atomicAdd(&cnt[ei[EE + e]], 1);   // dst
    if (e < LL * 4 * 64 * 64) {
        int l = e >> 14; int j = (e >> 12) & 3; int col = (e >> 6) & 63; int k = e & 63;
        const float* W = (j == 0 ? Wq : j == 1 ? Wk : j == 2 ? Wv : Ws) + l * 4096;
        float v = W[k * 64 + col];
        if (j == 0) v *= QSCL;
        wtb[e] = f2bf(v);
    }
    if (e < LL * 4 * 64) {
        int l = e >> 8; int j = (e >> 6) & 3; int c = e & 63;
        const float* bsrc = (j == 0 ? bq : j == 1 ? bk : j == 2 ? bv : bs) + l * 64;
        bprep[e] = bsrc[c] * (j == 0 ? QSCL : 1.0f);
    }
}

// single block, 1024 threads, 10 nodes/thread serial + one block scan.
// outputs: rp[n] = padded start (pad-16), degv[n] = real degree, cursor[n] = rp[n]
__global__ __launch_bounds__(1024) void k_scan(int* __restrict__ cnt,      // in: counts (== cursor buf)
                                               int* __restrict__ rp,
                                               int* __restrict__ degv) {
    __shared__ int ssum[1024];
    int t = threadIdx.x;
    int base = t * 10;
    int loc[10];
    int s = 0;
#pragma unroll
    for (int j = 0; j < 10; ++j) {
        int i = base + j;
        int d = (i < NN) ? cnt[i] : 0;
        loc[j] = d;
        s += (d + 15) & ~15;
    }
    ssum[t] = s;
    __syncthreads();
    for (int off = 1; off < 1024; off <<= 1) {
        int v = (t >= off) ? ssum[t - off] : 0;
        __syncthreads();
        ssum[t] += v;
        __syncthreads();
    }
    int run = ssum[t] - s;   // exclusive prefix of padded sizes
#pragma unroll
    for (int j = 0; j < 10; ++j) {
        int i = base + j;
        if (i < NN) {
            rp[i]   = run;
            degv[i] = loc[j];
            cnt[i]  = run;           // cursor for fill
            run += (loc[j] + 15) & ~15;
        }
    }
}

__global__ __launch_bounds__(256) void k_fill(const int* __restrict__ ei, int* __restrict__ cursor,
                                              int* __restrict__ csr) {
    int e = blockIdx.x * 256 + threadIdx.x;
    if (e >= EE) return;
    int dst = ei[EE + e];
    int pos = atomicAdd(&cursor[dst], 1);
    csr[pos] = ei[e] << 8;            // byte offset of 256B interleaved kv row
}

// ---------------- MFMA GEMM (swapped operands): one block per 64-row tile ----------------
// wave w: w=0 qh (fp16, pre-scaled), w=1 k -> kv (fp16), w=2 v -> kv (fp16), w=3 h += skip.
// A = weight frag [col][k], B = h frag [row][k]  =>  D: lane&15 = ROW, (lane>>4)*4+reg = COL
// kv row layout (256B): per 4-channel block j: [k_ch4 (8B fp16) | v_ch4 (8B fp16)] at j*16B.
// first!=0: compute input projection for this block's 64 rows before the GEMM.
__global__ __launch_bounds__(256, 4) void k_gemm(const float* __restrict__ x,
                                                 const float* __restrict__ inW,
                                                 const float* __restrict__ inb,
                                                 int first,
                                                 unsigned short* hb,
                                                 float* h,
                                                 const unsigned short* __restrict__ wtb,   // + layer off
                                                 const float* __restrict__ bprep,          // + layer off
                                                 unsigned short* __restrict__ qh,
                                                 unsigned short* __restrict__ kv) {
    int tid = threadIdx.x;
    int l = tid & 63, w = tid >> 6;
    int row0 = blockIdx.x * 64;
    int colb = l & 15, kg = l >> 4, rquad = kg;

    if (first) {
        int c = tid & 63;
        int rb = tid >> 6;
        for (int j = 0; j < 16; ++j) {
            int row = row0 + rb + j * 4;
            int b = row / NN;
            int n = row - b * NN;
            float s = inb[c];
#pragma unroll
            for (int t = 0; t < SS; ++t)
                s += x[((size_t)b * SS + t) * NN + n] * inW[t * 64 + c];
            h[(size_t)row * 64 + c]  = s;
            hb[(size_t)row * 64 + c] = f2bf(s);
        }
        __syncthreads();
    }

    const unsigned short* wb = wtb + (size_t)w * 4096;   // [col][k]
    bf8_t wfr[2][4];
#pragma unroll
    for (int ks = 0; ks < 2; ++ks)
#pragma unroll
        for (int ct = 0; ct < 4; ++ct)
            wfr[ks][ct] = *(const bf8_t*)(wb + (ct * 16 + colb) * 64 + ks * 32 + kg * 8);
    float4 biasv[4];
#pragma unroll
    for (int ct = 0; ct < 4; ++ct)
        biasv[ct] = *(const float4*)(bprep + w * 64 + ct * 16 + rquad * 4);

#pragma unroll
    for (int rt = 0; rt < 4; ++rt) {
        bf8_t hfr[2];
#pragma unroll
        for (int ks = 0; ks < 2; ++ks)
            hfr[ks] = *(const bf8_t*)(hb + (size_t)(row0 + rt * 16 + colb) * 64 + ks * 32 + kg * 8);
        f4_t acc[4];
#pragma unroll
        for (int ct = 0; ct < 4; ++ct) acc[ct] = (f4_t){0.f, 0.f, 0.f, 0.f};
#pragma unroll
        for (int ks = 0; ks < 2; ++ks)
#pragma unroll
            for (int ct = 0; ct < 4; ++ct)
                acc[ct] = __builtin_amdgcn_mfma_f32_16x16x32_bf16(wfr[ks][ct], hfr[ks], acc[ct], 0, 0, 0);

        int rowid = row0 + rt * 16 + colb;              // lane's row
        size_t rowoff = (size_t)rowid * 64;
#pragma unroll
        for (int ct = 0; ct < 4; ++ct) {
            int c0 = ct * 16 + rquad * 4;
            float v0 = acc[ct][0] + biasv[ct].x;
            float v1 = acc[ct][1] + biasv[ct].y;
            float v2 = acc[ct][2] + biasv[ct].z;
            float v3 = acc[ct][3] + biasv[ct].w;
            if (w == 0) {
                ushort4 st = {f2h(v0), f2h(v1), f2h(v2), f2h(v3)};
                *(ushort4*)(qh + rowoff + c0) = st;
            } else if (w == 1) {
                ushort4 st = {f2h(v0), f2h(v1), f2h(v2), f2h(v3)};
                *(ushort4*)(kv + (size_t)rowid * 128 + ((c0 >> 2) << 3)) = st;      // k slot
            } else if (w == 2) {
                ushort4 st = {f2h(v0), f2h(v1), f2h(v2), f2h(v3)};
                *(ushort4*)(kv + (size_t)rowid * 128 + ((c0 >> 2) << 3) + 4) = st;  // v slot
            } else {
                float4 hv = *(float4*)(h + rowoff + c0);
                hv.x += v0; hv.y += v1; hv.z += v2; hv.w += v3;
                *(float4*)(h + rowoff + c0) = hv;     // residual base = h + skip
            }
        }
    }
}

// ---------------- fused attention gather + residual + layernorm (+ out proj on last) ----
// grid = 20000: b = bid&7 (XCD affinity; kv per batch = 2.5MB fits 4MB L2)
// 16 edges/wave/iter; slot-s edge of group grp = e + grp*4 + s (one int4 csr load/lane)
// one dwordx4 kv gather per edge; fma_mix f32<-fp16 accumulation; DPP reductions
__global__ __launch_bounds__(256, 8) void k_attn_ln(const unsigned short* __restrict__ qh,
                                                    const unsigned short* __restrict__ kv,
                                                    const int* __restrict__ rp,
                                                    const int* __restrict__ degv,
                                                    const int* __restrict__ csr,
                                                    const float* __restrict__ lng,
                                                    const float* __restrict__ lnb,
                                                    float* __restrict__ h,
                                                    unsigned short* __restrict__ hb,
                                                    const float* __restrict__ oW,   // null except last layer
                                                    const float* __restrict__ ob,
                                                    float* __restrict__ out) {
    int b    = blockIdx.x & 7;
    int n    = ((blockIdx.x >> 3) << 2) | __builtin_amdgcn_readfirstlane(threadIdx.x >> 6);
    int lane = threadIdx.x & 63;
    int lg   = lane & 15;       // channel block: channels 4*lg..4*lg+3, head = lg>>2
    int grp  = lane >> 4;       // edge sub-group 0..3
    size_t wid = (size_t)b * NN + n;

    const char* kvbase = (const char*)kv + (size_t)b * NN * 256;   // wave-uniform
    int lgoff = lg * 16;

    uint2 qp = ((const uint2*)qh)[wid * 16 + lg];   // 4 fp16 (pre-scaled, log2 domain)

    int e0 = rp[n], deg = degv[n];
    int nf  = deg >> 4;         // full 16-edge chunks
    int rem = deg & 15;
    float den0 = 0.f, den1 = 0.f;
    float4 av0 = {0.f, 0.f, 0.f, 0.f}, av1 = {0.f, 0.f, 0.f, 0.f};

    int e = e0;
    for (int f = 0; f < nf; ++f, e += 16) {
        int4 cc = *(const int4*)(csr + e + grp * 4);     // this group's 4 edges
        unsigned o0 = (unsigned)(cc.x + lgoff);
        unsigned o1 = (unsigned)(cc.y + lgoff);
        unsigned o2 = (unsigned)(cc.z + lgoff);
        unsigned o3 = (unsigned)(cc.w + lgoff);
        uint4 a0 = *(const uint4*)(kvbase + o0);         // x,y = k 4ch; z,w = v 4ch
        uint4 a1 = *(const uint4*)(kvbase + o1);
        uint4 a2 = *(const uint4*)(kvbase + o2);
        uint4 a3 = *(const uint4*)(kvbase + o3);

        float d0 = dot2(a0.y, qp.y, dot2(a0.x, qp.x, 0.f));
        float d1 = dot2(a1.y, qp.y, dot2(a1.x, qp.x, 0.f));
        float d2 = dot2(a2.y, qp.y, dot2(a2.x, qp.x, 0.f));
        float d3 = dot2(a3.y, qp.y, dot2(a3.x, qp.x, 0.f));
        d0 = quad_sum(d0); d1 = quad_sum(d1);
        d2 = quad_sum(d2); d3 = quad_sum(d3);

        float w0 = __builtin_amdgcn_exp2f(d0);
        float w1 = __builtin_amdgcn_exp2f(d1);
        float w2 = __builtin_amdgcn_exp2f(d2);
        float w3 = __builtin_amdgcn_exp2f(d3);

        den0 += w0 + w1;
        den1 += w2 + w3;
        av0.x = fma_mixlo(a0.z, w0, av0.x); av0.x = fma_mixlo(a1.z, w1, av0.x);
        av0.y = fma_mixhi(a0.z, w0, av0.y); av0.y = fma_mixhi(a1.z, w1, av0.y);
        av0.z = fma_mixlo(a0.w, w0, av0.z); av0.z = fma_mixlo(a1.w, w1, av0.z);
        av0.w = fma_mixhi(a0.w, w0, av0.w); av0.w = fma_mixhi(a1.w, w1, av0.w);
        av1.x = fma_mixlo(a2.z, w2, av1.x); av1.x = fma_mixlo(a3.z, w3, av1.x);
        av1.y = fma_mixhi(a2.z, w2, av1.y); av1.y = fma_mixhi(a3.z, w3, av1.y);
        av1.z = fma_mixlo(a2.w, w2, av1.z); av1.z = fma_mixlo(a3.w, w3, av1.z);
        av1.w = fma_mixhi(a2.w, w2, av1.w); av1.w = fma_mixhi(a3.w, w3, av1.w);
    }
    if (rem) {
        int4 cc = *(const int4*)(csr + e + grp * 4);     // padding slots -> offset 0 (safe)
        unsigned o0 = (unsigned)(cc.x + lgoff);
        unsigned o1 = (unsigned)(cc.y + lgoff);
        unsigned o2 = (unsigned)(cc.z + lgoff);
        unsigned o3 = (unsigned)(cc.w + lgoff);
        uint4 a0 = *(const uint4*)(kvbase + o0);
        uint4 a1 = *(const uint4*)(kvbase + o1);
        uint4 a2 = *(const uint4*)(kvbase + o2);
        uint4 a3 = *(const uint4*)(kvbase + o3);

        int eb = grp * 4;
        float m0 = (eb + 0 < rem) ? 1.f : 0.f;
        float m1 = (eb + 1 < rem) ? 1.f : 0.f;
        float m2 = (eb + 2 < rem) ? 1.f : 0.f;
        float m3 = (eb + 3 < rem) ? 1.f : 0.f;

        float d0 = dot2(a0.y, qp.y, dot2(a0.x, qp.x, 0.f));
        float d1 = dot2(a1.y, qp.y, dot2(a1.x, qp.x, 0.f));
        float d2 = dot2(a2.y, qp.y, dot2(a2.x, qp.x, 0.f));
        float d3 = dot2(a3.y, qp.y, dot2(a3.x, qp.x, 0.f));
        d0 = quad_sum(d0); d1 = quad_sum(d1);
        d2 = quad_sum(d2); d3 = quad_sum(d3);

        float w0 = m0 * __builtin_amdgcn_exp2f(d0);
        float w1 = m1 * __builtin_amdgcn_exp2f(d1);
        float w2 = m2 * __builtin_amdgcn_exp2f(d2);
        float w3 = m3 * __builtin_amdgcn_exp2f(d3);

        den0 += w0 + w1;
        den1 += w2 + w3;
        av0.x = fma_mixlo(a0.z, w0, av0.x); av0.x = fma_mixlo(a1.z, w1, av0.x);
        av0.y = fma_mixhi(a0.z, w0, av0.y); av0.y = fma_mixhi(a1.z, w1, av0.y);
        av0.z = fma_mixlo(a0.w, w0, av0.z); av0.z = fma_mixlo(a1.w, w1, av0.z);
        av0.w = fma_mixhi(a0.w, w0, av0.w); av0.w = fma_mixhi(a1.w, w1, av0.w);
        av1.x = fma_mixlo(a2.z, w2, av1.x); av1.x = fma_mixlo(a3.z, w3, av1.x);
        av1.y = fma_mixhi(a2.z, w2, av1.y); av1.y = fma_mixhi(a3.z, w3, av1.y);
        av1.z = fma_mixlo(a2.w, w2, av1.z); av1.z = fma_mixlo(a3.w, w3, av1.z);
        av1.w = fma_mixhi(a2.w, w2, av1.w); av1.w = fma_mixhi(a3.w, w3, av1.w);
    }

    float den = den0 + den1;
    float4 av = {av0.x + av1.x, av0.y + av1.y, av0.z + av1.z, av0.w + av1.w};

    // merge the 4 edge-groups: pure sums (shared softmax reference m=0)
#pragma unroll
    for (int off = 16; off <= 32; off <<= 1) {
        den  += __shfl_xor(den, off);
        av.x += __shfl_xor(av.x, off); av.y += __shfl_xor(av.y, off);
        av.z += __shfl_xor(av.z, off); av.w += __shfl_xor(av.w, off);
    }
    float inv = (den > 0.f) ? __builtin_amdgcn_rcpf(den) : 0.f;

    // residual (h already holds h + skip) + layernorm (DPP 16-lane sums)
    float4 h4 = ((const float4*)h)[wid * 16 + lg];
    float4 x4;
    x4.x = h4.x + av.x * inv; x4.y = h4.y + av.y * inv;
    x4.z = h4.z + av.z * inv; x4.w = h4.w + av.w * inv;

    float s = row_sum(x4.x + x4.y + x4.z + x4.w);
    float mu = s * (1.f / 64.f);
    float4 dx;
    dx.x = x4.x - mu; dx.y = x4.y - mu; dx.z = x4.z - mu; dx.w = x4.w - mu;
    float vs = row_sum(dx.x * dx.x + dx.y * dx.y + dx.z * dx.z + dx.w * dx.w);
    float r = __builtin_amdgcn_rsqf(vs * (1.f / 64.f) + 1e-5f);

    float4 g4 = ((const float4*)lng)[lg];
    float4 b4 = ((const float4*)lnb)[lg];
    float4 o4;
    o4.x = dx.x * r * g4.x + b4.x; o4.y = dx.y * r * g4.y + b4.y;
    o4.z = dx.z * r * g4.z + b4.z; o4.w = dx.w * r * g4.w + b4.w;

    if (oW) {
        // fused output projection: t_p = sum_c o4[c] * oW[c][p]; DPP row reduce
        int c0 = lg * 4;
        float t0 = o4.x * oW[(c0+0)*3+0] + o4.y * oW[(c0+1)*3+0] + o4.z * oW[(c0+2)*3+0] + o4.w * oW[(c0+3)*3+0];
        float t1 = o4.x * oW[(c0+0)*3+1] + o4.y * oW[(c0+1)*3+1] + o4.z * oW[(c0+2)*3+1] + o4.w * oW[(c0+3)*3+1];
        float t2 = o4.x * oW[(c0+0)*3+2] + o4.y * oW[(c0+1)*3+2] + o4.z * oW[(c0+2)*3+2] + o4.w * oW[(c0+3)*3+2];
        t0 = row_sum(t0); t1 = row_sum(t1); t2 = row_sum(t2);
        if (lane == 0) {
            out[((size_t)b * PP + 0) * NN + n] = t0 + ob[0];
            out[((size_t)b * PP + 1) * NN + n] = t1 + ob[1];
            out[((size_t)b * PP + 2) * NN + n] = t2 + ob[2];
        }
    } else if (lane < 16) {
        ((float4*)h)[wid * 16 + lg] = o4;
        ushort4 hu = {f2bf(o4.x), f2bf(o4.y), f2bf(o4.z), f2bf(o4.w)};
        ((ushort4*)hb)[wid * 16 + lg] = hu;
    }
}

extern "C" void kernel_launch(void* const* d_in, const int* in_sizes, int n_in,
                              void* d_out, int out_size, void* d_ws, size_t ws_size,
                              hipStream_t stream) {
    const float* x    = (const float*)d_in[0];
    const int*   ei   = (const int*)  d_in[1];
    const float* inW  = (const float*)d_in[2];
    const float* inb  = (const float*)d_in[3];
    const float* Wq   = (const float*)d_in[4];
    const float* bq   = (const float*)d_in[5];
    const float* Wk   = (const float*)d_in[6];
    const float* bk   = (const float*)d_in[7];
    const float* Wv   = (const float*)d_in[8];
    const float* bv   = (const float*)d_in[9];
    const float* Wsk  = (const float*)d_in[10];
    const float* bsk  = (const float*)d_in[11];
    const float* lng  = (const float*)d_in[12];
    const float* lnb  = (const float*)d_in[13];
    const float* outW = (const float*)d_in[14];
    const float* outb = (const float*)d_in[15];
    float* out = (float*)d_out;

    float* h    = (float*)d_ws;                                       // BN*64 f32
    unsigned short* hb = (unsigned short*)(h + (size_t)BN * 64);      // BN*64 bf16
    unsigned short* qh = hb + (size_t)BN * 64;                        // BN*64 fp16
    unsigned short* kv = qh + (size_t)BN * 64;                        // BN*128 fp16 (k|v interleaved)
    int* rp      = (int*)(kv + (size_t)BN * 128);
    int* degv    = rp + NN;
    int* cursor  = degv + NN;
    int* csr     = cursor + NN;                          // CSR_CAP entries
    unsigned short* wtb = (unsigned short*)(csr + CSR_CAP);  // LL*4*64*64 bf16
    float* bprep = (float*)(wtb + LL * 4 * 64 * 64);         // LL*4*64 f32

    // CSR build + weight prep (edge list/weights constant across layers/batches)
    hipMemsetAsync(cursor, 0, (NN + CSR_CAP) * sizeof(int), stream);   // cursor + csr
    k_count<<<(EE + 255) / 256, 256, 0, stream>>>(ei, cursor, Wq, Wk, Wv, Wsk,
                                                  bq, bk, bv, bsk, wtb, bprep);
    k_scan <<<1, 1024, 0, stream>>>(cursor, rp, degv);
    k_fill <<<(EE + 255) / 256, 256, 0, stream>>>(ei, cursor, csr);

    for (int l = 0; l < LL; ++l) {
        k_gemm<<<BN / 64, 256, 0, stream>>>(x, inW, inb, (l == 0) ? 1 : 0, hb, h,
                                            wtb + (size_t)l * 4 * 4096,
                                            bprep + (size_t)l * 4 * 64, qh, kv);
        k_attn_ln<<<BN / 4, 256, 0, stream>>>(qh, kv, rp, degv, csr,
                                              lng, lnb, h, hb,
                                              (l == LL - 1) ? outW : nullptr, outb, out);
    }
}